// Round 4
// baseline (1550.684 us; speedup 1.0000x reference)
//
#include <hip/hip_runtime.h>

typedef unsigned short u16;
typedef u16  u16x2  __attribute__((ext_vector_type(2)));
typedef u16  u16x4  __attribute__((ext_vector_type(4)));
typedef u16  u16x8  __attribute__((ext_vector_type(8)));
typedef float f32x4 __attribute__((ext_vector_type(4)));
typedef __bf16 bf16x8 __attribute__((ext_vector_type(8)));

#define D_MODEL 1024
#define DFF     4096
#define SEQ     4096
#define BATCH   4
#define NHEAD   16
#define MROWS   (BATCH*SEQ)   /* 16384 */
#define MCHUNK  4096          /* FFN row-chunk (4 chunks) */

#define BM 128
#define BN 128
#define BK 32

__device__ __forceinline__ float bf2f(u16 u) {
  unsigned v = ((unsigned)u) << 16;
  return __builtin_bit_cast(float, v);
}
__device__ __forceinline__ u16 f2bf(float f) {
  unsigned u = __builtin_bit_cast(unsigned, f);
  u += 0x7fffu + ((u >> 16) & 1u);
  return (u16)(u >> 16);
}

// async global->LDS DMA, 16B per lane. LDS dest must be wave-uniform base;
// HW writes base + lane*16. Global src is per-lane.
__device__ __forceinline__ void gload16(void* lds, const void* g) {
  __builtin_amdgcn_global_load_lds(
      (const __attribute__((address_space(1))) unsigned*)g,
      (__attribute__((address_space(3))) unsigned*)lds, 16, 0, 0);
}

// ---------------- transpose fp32 -> bf16: Wt[n][k] = bf16(W[k][n]) ---------
__global__ __launch_bounds__(256)
void transpose_kernel(const float* __restrict__ W, u16* __restrict__ Wt, int K, int N)
{
  __shared__ u16 tile[32][33];
  const int n0 = blockIdx.x * 32, k0 = blockIdx.y * 32;
  const int tx = threadIdx.x & 31, ty = threadIdx.x >> 5;   // 32 x 8
#pragma unroll
  for (int r = ty; r < 32; r += 8)
    tile[r][tx] = f2bf(W[(size_t)(k0 + r) * N + n0 + tx]);
  __syncthreads();
#pragma unroll
  for (int r = ty; r < 32; r += 8)
    Wt[(size_t)(n0 + r) * K + k0 + tx] = tile[tx][r];
}

// ---------------- LayerNorm: T in (fp32 or bf16) -> bf16 out ---------------
template<typename T>
__global__ __launch_bounds__(256)
void ln_kernel(const T* __restrict__ x, const float* __restrict__ g,
               const float* __restrict__ be, u16* __restrict__ out)
{
  const int row = blockIdx.x;
  const int t = threadIdx.x;
  float v0, v1, v2, v3;
  if constexpr (sizeof(T) == 4) {
    f32x4 u = ((const f32x4*)((const float*)x + (size_t)row * D_MODEL))[t];
    v0 = u.x; v1 = u.y; v2 = u.z; v3 = u.w;
  } else {
    u16x4 u = ((const u16x4*)((const u16*)x + (size_t)row * D_MODEL))[t];
    v0 = bf2f(u.x); v1 = bf2f(u.y); v2 = bf2f(u.z); v3 = bf2f(u.w);
  }
  float s  = v0 + v1 + v2 + v3;
  float s2 = v0*v0 + v1*v1 + v2*v2 + v3*v3;
#pragma unroll
  for (int off = 32; off > 0; off >>= 1) {
    s  += __shfl_down(s,  off);
    s2 += __shfl_down(s2, off);
  }
  __shared__ float red[8];
  if ((t & 63) == 0) { red[t >> 6] = s; red[4 + (t >> 6)] = s2; }
  __syncthreads();
  float S  = red[0] + red[1] + red[2] + red[3];
  float S2 = red[4] + red[5] + red[6] + red[7];
  float mu  = S * (1.f / D_MODEL);
  float var = S2 * (1.f / D_MODEL) - mu * mu;
  var = fmaxf(var, 0.f);
  float rs  = rsqrtf(var + 1e-5f);
  f32x4 gu = ((const f32x4*)g)[t];
  f32x4 bu = ((const f32x4*)be)[t];
  u16x4 o;
  o.x = f2bf((v0 - mu) * rs * gu.x + bu.x);
  o.y = f2bf((v1 - mu) * rs * gu.y + bu.y);
  o.z = f2bf((v2 - mu) * rs * gu.z + bu.z);
  o.w = f2bf((v3 - mu) * rs * gu.w + bu.w);
  ((u16x4*)(out + (size_t)row * D_MODEL))[t] = o;
}

// ---------------- GEMM: C = A(MxK,bf16) @ Bt(NxK,bf16)^T + bias(fp32) ------
// LDS layout is k-chunk-major: 16B slot p holds row (p&127), k-chunk (p>>7).
// Achieved by per-lane source remap (LDS dest stays linear for gload_lds).
// Fragment ds_read_b128: consecutive lanes -> consecutive 16B slots => 2-way
// bank aliasing only (free), vs 8-way with row-major [row][BK] layout.
// MODE 0: bf16 out = acc+bias
// MODE 1: bf16 out = elu(acc+bias)+1
// MODE 2: bf16 out = acc+bias + res_fp32
// MODE 3: FP32 out = acc+bias + res_bf16   (final output)
template<int MODE>
__global__ __launch_bounds__(256, 2)
void gemm_kernel(const u16* __restrict__ A, const u16* __restrict__ Bt,
                 const float* __restrict__ bias, const void* __restrict__ resv,
                 void* __restrict__ outv, int N, int K)
{
  __shared__ __align__(16) u16 lA[2][BM * BK];
  __shared__ __align__(16) u16 lB[2][BN * BK];
  const float* resf = (const float*)resv;
  const u16*   resb = (const u16*)resv;
  const int tid = threadIdx.x;
  const int wave = tid >> 6, lane = tid & 63;
  const int quad = lane >> 4, ln = lane & 15;
  const int bm = blockIdx.y * BM, bn = blockIdx.x * BN;
  const int wm = (wave >> 1) * 64, wn = (wave & 1) * 64;

  f32x4 acc[4][4] = {};

  // k-major staging: slot p=tid -> row tid&127, chunk tid>>7; p=tid+256 -> chunk +2
  const int rr = tid & 127, qq = tid >> 7;
  const u16* gA0 = A  + (size_t)(bm + rr) * K + qq * 8;
  const u16* gA1 = gA0 + 16;
  const u16* gB0 = Bt + (size_t)(bn + rr) * K + qq * 8;
  const u16* gB1 = gB0 + 16;
  // per-wave-uniform LDS dest offsets (u16 units; lane*16B added by HW)
  const int d0 = wave * 64 * 8;
  const int d1 = (256 + wave * 64) * 8;

  // prologue: stage tile 0 into buf 0
  gload16(&lA[0][d0], gA0);
  gload16(&lA[0][d1], gA1);
  gload16(&lB[0][d0], gB0);
  gload16(&lB[0][d1], gB1);
  __syncthreads();

  int cur = 0;
  for (int k0 = 0; k0 < K; k0 += BK) {
    const int nxt = cur ^ 1;
    if (k0 + BK < K) {               // issue next-tile loads (hidden by compute)
      gload16(&lA[nxt][d0], gA0 + k0 + BK);
      gload16(&lA[nxt][d1], gA1 + k0 + BK);
      gload16(&lB[nxt][d0], gB0 + k0 + BK);
      gload16(&lB[nxt][d1], gB1 + k0 + BK);
    }
    bf16x8 af[4], bfr[4];
#pragma unroll
    for (int i = 0; i < 4; ++i) {
      af[i]  = *(const bf16x8*)&lA[cur][(quad * 128 + wm + i * 16 + ln) * 8];
      bfr[i] = *(const bf16x8*)&lB[cur][(quad * 128 + wn + i * 16 + ln) * 8];
    }
#pragma unroll
    for (int i = 0; i < 4; ++i)
#pragma unroll
      for (int j = 0; j < 4; ++j)
        acc[i][j] = __builtin_amdgcn_mfma_f32_16x16x32_bf16(af[i], bfr[j], acc[i][j], 0, 0, 0);
    __syncthreads();                 // drains vmcnt(0): next buf ready
    cur = nxt;
  }

#pragma unroll
  for (int j = 0; j < 4; ++j) {
    const int col = bn + wn + j * 16 + ln;
    const float bv = bias[col];
#pragma unroll
    for (int i = 0; i < 4; ++i) {
#pragma unroll
      for (int r = 0; r < 4; ++r) {
        const int row = bm + wm + i * 16 + quad * 4 + r;
        const size_t off = (size_t)row * N + col;
        float vv = acc[i][j][r] + bv;
        if (MODE == 1) vv = vv > 0.f ? vv + 1.f : __expf(vv);
        if (MODE == 2) vv += resf[off];
        if (MODE == 3) vv += bf2f(resb[off]);
        if (MODE == 3) ((float*)outv)[off] = vv;      // final output is fp32
        else           ((u16*)outv)[off]   = f2bf(vv);
      }
    }
  }
}

// ---------------- fused FFN1: out = gelu(A@Wg + bg) * (A@Wl + bl) ----------
__global__ __launch_bounds__(256, 2)
void ffn1_kernel(const u16* __restrict__ A, const u16* __restrict__ Wt,
                 const float* __restrict__ b1, u16* __restrict__ out, int K)
{
  __shared__ __align__(16) u16 lA [2][BM * BK];
  __shared__ __align__(16) u16 lBg[2][BN * BK];
  __shared__ __align__(16) u16 lBl[2][BN * BK];
  const int tid = threadIdx.x;
  const int wave = tid >> 6, lane = tid & 63;
  const int quad = lane >> 4, ln = lane & 15;
  const int bm = blockIdx.y * BM, bn = blockIdx.x * BN;
  const int wm = (wave >> 1) * 64, wn = (wave & 1) * 64;

  f32x4 accg[4][4] = {};
  f32x4 accl[4][4] = {};

  const int rr = tid & 127, qq = tid >> 7;
  const u16* gA0 = A  + (size_t)(bm + rr) * K + qq * 8;
  const u16* gA1 = gA0 + 16;
  const u16* gG0 = Wt + (size_t)(bn + rr) * K + qq * 8;
  const u16* gG1 = gG0 + 16;
  const u16* gL0 = Wt + (size_t)(DFF + bn + rr) * K + qq * 8;
  const u16* gL1 = gL0 + 16;
  const int d0 = wave * 64 * 8;
  const int d1 = (256 + wave * 64) * 8;

  // prologue: stage tile 0 into buf 0
  gload16(&lA [0][d0], gA0);
  gload16(&lA [0][d1], gA1);
  gload16(&lBg[0][d0], gG0);
  gload16(&lBg[0][d1], gG1);
  gload16(&lBl[0][d0], gL0);
  gload16(&lBl[0][d1], gL1);
  __syncthreads();

  int cur = 0;
  for (int k0 = 0; k0 < K; k0 += BK) {
    const int nxt = cur ^ 1;
    if (k0 + BK < K) {
      gload16(&lA [nxt][d0], gA0 + k0 + BK);
      gload16(&lA [nxt][d1], gA1 + k0 + BK);
      gload16(&lBg[nxt][d0], gG0 + k0 + BK);
      gload16(&lBg[nxt][d1], gG1 + k0 + BK);
      gload16(&lBl[nxt][d0], gL0 + k0 + BK);
      gload16(&lBl[nxt][d1], gL1 + k0 + BK);
    }
    bf16x8 af[4], bg[4], bl[4];
#pragma unroll
    for (int i = 0; i < 4; ++i) {
      af[i] = *(const bf16x8*)&lA [cur][(quad * 128 + wm + i * 16 + ln) * 8];
      bg[i] = *(const bf16x8*)&lBg[cur][(quad * 128 + wn + i * 16 + ln) * 8];
      bl[i] = *(const bf16x8*)&lBl[cur][(quad * 128 + wn + i * 16 + ln) * 8];
    }
#pragma unroll
    for (int i = 0; i < 4; ++i)
#pragma unroll
      for (int j = 0; j < 4; ++j) {
        accg[i][j] = __builtin_amdgcn_mfma_f32_16x16x32_bf16(af[i], bg[j], accg[i][j], 0, 0, 0);
        accl[i][j] = __builtin_amdgcn_mfma_f32_16x16x32_bf16(af[i], bl[j], accl[i][j], 0, 0, 0);
      }
    __syncthreads();
    cur = nxt;
  }

#pragma unroll
  for (int j = 0; j < 4; ++j) {
    const int col = bn + wn + j * 16 + ln;
    const float bgv = b1[col];
    const float blv = b1[DFF + col];
#pragma unroll
    for (int i = 0; i < 4; ++i) {
#pragma unroll
      for (int r = 0; r < 4; ++r) {
        const int row = bm + wm + i * 16 + quad * 4 + r;
        float gg = accg[i][j][r] + bgv;
        float ll = accl[i][j][r] + blv;
        float ge = 0.5f * gg * (1.f + erff(gg * 0.70710678118f));
        out[(size_t)row * DFF + col] = f2bf(ge * ll);
      }
    }
  }
}

// ---------------- kv = K^T @ V via MFMA (per b,h; fp32 partials) -----------
// grid: 64 bh * 4 s-chunks = 256 blocks, 256 threads (4 waves).
// Each block: M=64(d) x N=64(e) x K=1024(s) GEMM slice.
// LDS tiles [32 s][64+2] (pad=2 -> transposed frag reads ~conflict-free).
#define KVCH 1024
__global__ __launch_bounds__(256)
void kvmm_kernel(const u16* __restrict__ kk, const u16* __restrict__ vv,
                 float* __restrict__ kvpart)
{
  __shared__ __align__(16) u16 lK[32][66];
  __shared__ __align__(16) u16 lV[32][66];
  const int blk = blockIdx.x;
  const int c = blk & 3, bh = blk >> 2;
  const int b = bh >> 4, h = bh & 15;
  const int tid = threadIdx.x, wave = tid >> 6, lane = tid & 63;
  const int quad = lane >> 4, ln = lane & 15;
  const int dbase = (wave >> 1) * 32, ebase = (wave & 1) * 32;   // 32x32 quadrant
  f32x4 acc[2][2] = {};

  const int srow = tid >> 3;         // 0..31
  const int dcol = (tid & 7) * 8;    // 0..56
  const size_t gbase = ((size_t)b * SEQ + (size_t)c * KVCH + srow) * D_MODEL + h * 64 + dcol;
  const u16* gk = kk + gbase;
  const u16* gv = vv + gbase;

  for (int s0 = 0; s0 < KVCH; s0 += 32) {
    u16x8 k8 = *(const u16x8*)(gk + (size_t)s0 * D_MODEL);
    u16x8 v8 = *(const u16x8*)(gv + (size_t)s0 * D_MODEL);
    __syncthreads();
    u16x2* wk2 = (u16x2*)&lK[srow][dcol];
    u16x2* wv2 = (u16x2*)&lV[srow][dcol];
#pragma unroll
    for (int p = 0; p < 4; ++p) {
      u16x2 a; a.x = k8[2*p]; a.y = k8[2*p+1]; wk2[p] = a;
      u16x2 w; w.x = v8[2*p]; w.y = v8[2*p+1]; wv2[p] = w;
    }
    __syncthreads();
    bf16x8 af[2], bf[2];
#pragma unroll
    for (int i = 0; i < 2; ++i) {
      const int dd = dbase + i * 16 + ln;
      const int ee = ebase + i * 16 + ln;
      u16x8 at, bt;
#pragma unroll
      for (int j = 0; j < 8; ++j) {
        at[j] = lK[quad * 8 + j][dd];
        bt[j] = lV[quad * 8 + j][ee];
      }
      af[i] = __builtin_bit_cast(bf16x8, at);
      bf[i] = __builtin_bit_cast(bf16x8, bt);
    }
#pragma unroll
    for (int i = 0; i < 2; ++i)
#pragma unroll
      for (int j = 0; j < 2; ++j)
        acc[i][j] = __builtin_amdgcn_mfma_f32_16x16x32_bf16(af[i], bf[j], acc[i][j], 0, 0, 0);
  }

  float* op = kvpart + ((size_t)c * 64 + bh) * 4096;   // [c][bh][d][e]
#pragma unroll
  for (int i = 0; i < 2; ++i)
#pragma unroll
    for (int j = 0; j < 2; ++j)
#pragma unroll
      for (int r = 0; r < 4; ++r) {
        const int d = dbase + i * 16 + quad * 4 + r;
        const int e = ebase + j * 16 + ln;
        op[d * 64 + e] = acc[i][j][r];
      }
}

// sum 4 partials in place: p[i] = sum_c p[c*262144 + i]   (f32x4 vectorized)
__global__ __launch_bounds__(256)
void kvreduce_kernel(float* __restrict__ p)
{
  const int i = blockIdx.x * 256 + threadIdx.x;   // grid 256 -> 65536 f32x4
  f32x4* p4 = (f32x4*)p;
  f32x4 a = p4[i];
  f32x4 b = p4[i + 65536];
  f32x4 c = p4[i + 131072];
  f32x4 d = p4[i + 196608];
  p4[i] = (a + b) + (c + d);
}

// ---------------- attn[s,e] = sum_d q[s,d]*kv[d,e] -------------------------
__global__ __launch_bounds__(256)
void attn_kernel(const u16* __restrict__ qq, const float* __restrict__ kv,
                 u16* __restrict__ out)
{
  __shared__ __align__(16) float kvs[64 * 64];
  const int blk = blockIdx.x;          // (bh)*64 + schunk
  const int sc = blk & 63;
  const int bh = blk >> 6;
  const int b = bh >> 4, h = bh & 15;
  const int t = threadIdx.x;
  const f32x4* src = (const f32x4*)(kv + (size_t)bh * 4096);
  for (int i = t; i < 1024; i += 256) ((f32x4*)kvs)[i] = src[i];
  __syncthreads();
  const int sl = t >> 2, e0 = (t & 3) * 16;
  const size_t row = (size_t)b * SEQ + sc * 64 + sl;
  const u16* qp = qq + row * D_MODEL + h * 64;
  float qv[64];
#pragma unroll
  for (int i = 0; i < 16; ++i) {
    u16x4 u = ((const u16x4*)qp)[i];
    qv[i*4+0] = bf2f(u.x); qv[i*4+1] = bf2f(u.y);
    qv[i*4+2] = bf2f(u.z); qv[i*4+3] = bf2f(u.w);
  }
  f32x4 acc[4] = {};
  for (int d = 0; d < 64; ++d) {
    const float qd = qv[d];
    const f32x4* kr = (const f32x4*)(kvs + d * 64 + e0);
#pragma unroll
    for (int i = 0; i < 4; ++i) acc[i] += qd * kr[i];
  }
  u16* op = out + row * D_MODEL + h * 64 + e0;
#pragma unroll
  for (int i = 0; i < 4; ++i) {
    u16x4 o;
    o.x = f2bf(acc[i][0]); o.y = f2bf(acc[i][1]);
    o.z = f2bf(acc[i][2]); o.w = f2bf(acc[i][3]);
    ((u16x4*)op)[i] = o;
  }
}

// ---------------------------------------------------------------------------
// Inputs fp32, OUTPUT FP32. Workspace (peak 128 MB), lifetime-packed:
//   [0,32)MB   : transposed bf16 weights; kvpart (4MB fp32) aliases wkt+wvt
//                (both dead after K/V gemms)
//   [32,64)MB  : hb (LN1 out, bf16)  -> x1b (attn+res, bf16)
//   [64,96)MB  : kb (K) -> qb (Q) -> hb2 (LN2)
//   [96,128)MB : vb (V) -> attnb -> gbuf (FFN chunk, 32MB)
extern "C" void kernel_launch(void* const* d_in, const int* in_sizes, int n_in,
                              void* d_out, int out_size, void* d_ws, size_t ws_size,
                              hipStream_t stream)
{
  const float* x   = (const float*)d_in[0];
  const float* wq  = (const float*)d_in[1];
  const float* bq  = (const float*)d_in[2];
  const float* wk  = (const float*)d_in[3];
  const float* bk  = (const float*)d_in[4];
  const float* wv  = (const float*)d_in[5];
  const float* bv  = (const float*)d_in[6];
  const float* wo  = (const float*)d_in[7];
  const float* bo  = (const float*)d_in[8];
  const float* w1  = (const float*)d_in[9];
  const float* b1  = (const float*)d_in[10];
  const float* w2  = (const float*)d_in[11];
  const float* b2  = (const float*)d_in[12];
  const float* g1  = (const float*)d_in[13];
  const float* be1 = (const float*)d_in[14];
  const float* g2  = (const float*)d_in[15];
  const float* be2 = (const float*)d_in[16];

  char* ws = (char*)d_ws;
  const size_t MB = 1024ull * 1024ull;
  u16* wqt = (u16*)(ws + 0 * MB);
  u16* wkt = (u16*)(ws + 2 * MB);
  u16* wvt = (u16*)(ws + 4 * MB);
  u16* wot = (u16*)(ws + 6 * MB);
  u16* w1t = (u16*)(ws + 8 * MB);    // 16 MB
  u16* w2t = (u16*)(ws + 24 * MB);   // 8 MB

  u16* hb    = (u16*)(ws + 32 * MB); // LN1 out
  u16* x1b   = (u16*)(ws + 32 * MB); // alias: hb dead after Q gemm
  u16* kb    = (u16*)(ws + 64 * MB);
  u16* qb    = (u16*)(ws + 64 * MB); // alias: kb dead after kvmm_kernel
  u16* hb2   = (u16*)(ws + 64 * MB); // alias: qb dead after attn
  u16* vb    = (u16*)(ws + 96 * MB);
  u16* attnb = (u16*)(ws + 96 * MB); // alias: vb dead after kvmm_kernel
  u16* gbuf  = (u16*)(ws + 96 * MB); // alias: attnb dead after O gemm
  float* kvpart = (float*)(ws + 2 * MB); // alias wkt+wvt: dead after K/V gemms (4MB)

  // weight transposes + fp32->bf16 (N x K layout)
  transpose_kernel<<<dim3(32, 32), 256, 0, stream>>>(wq, wqt, 1024, 1024);
  transpose_kernel<<<dim3(32, 32), 256, 0, stream>>>(wk, wkt, 1024, 1024);
  transpose_kernel<<<dim3(32, 32), 256, 0, stream>>>(wv, wvt, 1024, 1024);
  transpose_kernel<<<dim3(32, 32), 256, 0, stream>>>(wo, wot, 1024, 1024);
  transpose_kernel<<<dim3(256, 32), 256, 0, stream>>>(w1, w1t, 1024, 8192);
  transpose_kernel<<<dim3(32, 128), 256, 0, stream>>>(w2, w2t, 4096, 1024);

  // LN1 (fp32 in -> bf16 out)
  ln_kernel<float><<<MROWS, 256, 0, stream>>>(x, g1, be1, hb);

  dim3 gproj(D_MODEL / BN, MROWS / BM);   // (8,128)
  // K, V first (consumed into kv), then Q overwrites kb
  gemm_kernel<1><<<gproj, 256, 0, stream>>>(hb, wkt, bk, nullptr, kb, D_MODEL, D_MODEL);
  gemm_kernel<0><<<gproj, 256, 0, stream>>>(hb, wvt, bv, nullptr, vb, D_MODEL, D_MODEL);

  // kv = K^T @ V (MFMA, 4 s-chunk partials + reduce; no atomics)
  kvmm_kernel<<<64 * 4, 256, 0, stream>>>(kb, vb, kvpart);
  kvreduce_kernel<<<256, 256, 0, stream>>>(kvpart);

  gemm_kernel<1><<<gproj, 256, 0, stream>>>(hb, wqt, bq, nullptr, qb, D_MODEL, D_MODEL);

  // attn = Q @ kv -> attnb (vb region)
  attn_kernel<<<BATCH * NHEAD * (SEQ / 64), 256, 0, stream>>>(qb, kvpart, attnb);

  // out projection + residual(x, fp32) -> x1b (hb region)
  gemm_kernel<2><<<gproj, 256, 0, stream>>>(attnb, wot, bo, x, x1b, D_MODEL, D_MODEL);

  // LN2 (bf16 in -> bf16 out) -> hb2 (qb region)
  ln_kernel<u16><<<MROWS, 256, 0, stream>>>(x1b, g2, be2, hb2);

  // FFN in row-chunks; gbuf (32 MB) reused per chunk; final out is FP32
  for (int c = 0; c < MROWS / MCHUNK; ++c) {
    const size_t ro = (size_t)c * MCHUNK;
    ffn1_kernel<<<dim3(DFF / BN, MCHUNK / BM), 256, 0, stream>>>(
        hb2 + ro * D_MODEL, w1t, b1, gbuf, D_MODEL);
    gemm_kernel<3><<<dim3(D_MODEL / BN, MCHUNK / BM), 256, 0, stream>>>(
        gbuf, w2t, b2, x1b + ro * D_MODEL, (float*)d_out + ro * D_MODEL, D_MODEL, DFF);
  }
}

// Round 5
// 1145.046 us; speedup vs baseline: 1.3543x; 1.3543x over previous
//
#include <hip/hip_runtime.h>

typedef unsigned short u16;
typedef u16  u16x2  __attribute__((ext_vector_type(2)));
typedef u16  u16x4  __attribute__((ext_vector_type(4)));
typedef u16  u16x8  __attribute__((ext_vector_type(8)));
typedef float f32x4 __attribute__((ext_vector_type(4)));
typedef __bf16 bf16x8 __attribute__((ext_vector_type(8)));

#define D_MODEL 1024
#define DFF     4096
#define SEQ     4096
#define BATCH   4
#define NHEAD   16
#define MROWS   (BATCH*SEQ)   /* 16384 */
#define MCHUNK  4096          /* FFN row-chunk (4 chunks) */

#define BM 128
#define BN 128
#define BK 32

__device__ __forceinline__ float bf2f(u16 u) {
  unsigned v = ((unsigned)u) << 16;
  return __builtin_bit_cast(float, v);
}
__device__ __forceinline__ u16 f2bf(float f) {
  unsigned u = __builtin_bit_cast(unsigned, f);
  u += 0x7fffu + ((u >> 16) & 1u);
  return (u16)(u >> 16);
}

// async global->LDS DMA, 16B per lane. LDS dest must be wave-uniform base;
// HW writes base + lane*16. Global src is per-lane.
__device__ __forceinline__ void gload16(void* lds, const void* g) {
  __builtin_amdgcn_global_load_lds(
      (const __attribute__((address_space(1))) unsigned*)g,
      (__attribute__((address_space(3))) unsigned*)lds, 16, 0, 0);
}

// T1: XCD-aware bijective block swizzle (grids here are all %8==0).
// XCD x executes a CONTIGUOUS chunk of work-items -> neighbor tiles sharing
// an A-panel stay in one XCD's L2.
__device__ __forceinline__ int xcd_swz_bid() {
  const int gx = gridDim.x;
  const int nwg = gx * gridDim.y;
  int bid = blockIdx.y * gx + blockIdx.x;
  const int cpx = nwg >> 3;
  return (bid & 7) * cpx + (bid >> 3);
}

// ---------------- transpose fp32 -> bf16: Wt[n][k] = bf16(W[k][n]) ---------
__global__ __launch_bounds__(256)
void transpose_kernel(const float* __restrict__ W, u16* __restrict__ Wt, int K, int N)
{
  __shared__ u16 tile[32][33];
  const int n0 = blockIdx.x * 32, k0 = blockIdx.y * 32;
  const int tx = threadIdx.x & 31, ty = threadIdx.x >> 5;   // 32 x 8
#pragma unroll
  for (int r = ty; r < 32; r += 8)
    tile[r][tx] = f2bf(W[(size_t)(k0 + r) * N + n0 + tx]);
  __syncthreads();
#pragma unroll
  for (int r = ty; r < 32; r += 8)
    Wt[(size_t)(n0 + r) * K + k0 + tx] = tile[tx][r];
}

// ---------------- LayerNorm: T in (fp32 or bf16) -> bf16 out ---------------
template<typename T>
__global__ __launch_bounds__(256)
void ln_kernel(const T* __restrict__ x, const float* __restrict__ g,
               const float* __restrict__ be, u16* __restrict__ out)
{
  const int row = blockIdx.x;
  const int t = threadIdx.x;
  float v0, v1, v2, v3;
  if constexpr (sizeof(T) == 4) {
    f32x4 u = ((const f32x4*)((const float*)x + (size_t)row * D_MODEL))[t];
    v0 = u.x; v1 = u.y; v2 = u.z; v3 = u.w;
  } else {
    u16x4 u = ((const u16x4*)((const u16*)x + (size_t)row * D_MODEL))[t];
    v0 = bf2f(u.x); v1 = bf2f(u.y); v2 = bf2f(u.z); v3 = bf2f(u.w);
  }
  float s  = v0 + v1 + v2 + v3;
  float s2 = v0*v0 + v1*v1 + v2*v2 + v3*v3;
#pragma unroll
  for (int off = 32; off > 0; off >>= 1) {
    s  += __shfl_down(s,  off);
    s2 += __shfl_down(s2, off);
  }
  __shared__ float red[8];
  if ((t & 63) == 0) { red[t >> 6] = s; red[4 + (t >> 6)] = s2; }
  __syncthreads();
  float S  = red[0] + red[1] + red[2] + red[3];
  float S2 = red[4] + red[5] + red[6] + red[7];
  float mu  = S * (1.f / D_MODEL);
  float var = S2 * (1.f / D_MODEL) - mu * mu;
  var = fmaxf(var, 0.f);
  float rs  = rsqrtf(var + 1e-5f);
  f32x4 gu = ((const f32x4*)g)[t];
  f32x4 bu = ((const f32x4*)be)[t];
  u16x4 o;
  o.x = f2bf((v0 - mu) * rs * gu.x + bu.x);
  o.y = f2bf((v1 - mu) * rs * gu.y + bu.y);
  o.z = f2bf((v2 - mu) * rs * gu.z + bu.z);
  o.w = f2bf((v3 - mu) * rs * gu.w + bu.w);
  ((u16x4*)(out + (size_t)row * D_MODEL))[t] = o;
}

// ---------------- GEMM: C = A(MxK,bf16) @ Bt(NxK,bf16)^T + bias(fp32) ------
// 2-phase double-buffer; coalesced row-major staging (16 rows x 64B per wave).
// MODE 0: bf16 out = acc+bias
// MODE 1: bf16 out = elu(acc+bias)+1
// MODE 2: bf16 out = acc+bias + res_fp32
// MODE 3: FP32 out = acc+bias + res_bf16   (final output)
template<int MODE>
__global__ __launch_bounds__(256, 2)
void gemm_kernel(const u16* __restrict__ A, const u16* __restrict__ Bt,
                 const float* __restrict__ bias, const void* __restrict__ resv,
                 void* __restrict__ outv, int N, int K)
{
  __shared__ __align__(16) u16 lA[2][BM * BK];
  __shared__ __align__(16) u16 lB[2][BN * BK];
  const float* resf = (const float*)resv;
  const u16*   resb = (const u16*)resv;
  const int tid = threadIdx.x;
  const int wave = tid >> 6, lane = tid & 63;
  const int quad = lane >> 4, ln = lane & 15;
  const int bid = xcd_swz_bid();
  const int bm = (bid / (int)gridDim.x) * BM, bn = (bid % (int)gridDim.x) * BN;
  const int wm = (wave >> 1) * 64, wn = (wave & 1) * 64;

  f32x4 acc[4][4] = {};

  const int c0 = tid,       r0 = c0 >> 2, q0 = c0 & 3;
  const int c1 = tid + 256, r1 = c1 >> 2, q1 = c1 & 3;
  const u16* gA0 = A  + (size_t)(bm + r0) * K + q0 * 8;
  const u16* gA1 = A  + (size_t)(bm + r1) * K + q1 * 8;
  const u16* gB0 = Bt + (size_t)(bn + r0) * K + q0 * 8;
  const u16* gB1 = Bt + (size_t)(bn + r1) * K + q1 * 8;
  // per-wave-uniform LDS dest offsets (u16 units; lane*16B added by HW)
  const int d0 = wave * 64 * 8;
  const int d1 = (256 + wave * 64) * 8;

  // prologue: stage tile 0 into buf 0
  gload16(&lA[0][d0], gA0);
  gload16(&lA[0][d1], gA1);
  gload16(&lB[0][d0], gB0);
  gload16(&lB[0][d1], gB1);
  __syncthreads();

  int cur = 0;
  for (int k0 = 0; k0 < K; k0 += BK) {
    const int nxt = cur ^ 1;
    if (k0 + BK < K) {               // issue next-tile loads (hidden by compute)
      gload16(&lA[nxt][d0], gA0 + k0 + BK);
      gload16(&lA[nxt][d1], gA1 + k0 + BK);
      gload16(&lB[nxt][d0], gB0 + k0 + BK);
      gload16(&lB[nxt][d1], gB1 + k0 + BK);
    }
    bf16x8 af[4], bfr[4];
#pragma unroll
    for (int i = 0; i < 4; ++i) {
      af[i]  = *(const bf16x8*)&lA[cur][(wm + i * 16 + ln) * BK + quad * 8];
      bfr[i] = *(const bf16x8*)&lB[cur][(wn + i * 16 + ln) * BK + quad * 8];
    }
#pragma unroll
    for (int i = 0; i < 4; ++i)
#pragma unroll
      for (int j = 0; j < 4; ++j)
        acc[i][j] = __builtin_amdgcn_mfma_f32_16x16x32_bf16(af[i], bfr[j], acc[i][j], 0, 0, 0);
    __syncthreads();                 // drains vmcnt(0): next buf ready
    cur = nxt;
  }

#pragma unroll
  for (int j = 0; j < 4; ++j) {
    const int col = bn + wn + j * 16 + ln;
    const float bv = bias[col];
#pragma unroll
    for (int i = 0; i < 4; ++i) {
#pragma unroll
      for (int r = 0; r < 4; ++r) {
        const int row = bm + wm + i * 16 + quad * 4 + r;
        const size_t off = (size_t)row * N + col;
        float vv = acc[i][j][r] + bv;
        if (MODE == 1) vv = vv > 0.f ? vv + 1.f : __expf(vv);
        if (MODE == 2) vv += resf[off];
        if (MODE == 3) vv += bf2f(resb[off]);
        if (MODE == 3) ((float*)outv)[off] = vv;      // final output is fp32
        else           ((u16*)outv)[off]   = f2bf(vv);
      }
    }
  }
}

// ---------------- fused FFN1: out = gelu(A@Wg + bg) * (A@Wl + bl) ----------
__global__ __launch_bounds__(256, 2)
void ffn1_kernel(const u16* __restrict__ A, const u16* __restrict__ Wt,
                 const float* __restrict__ b1, u16* __restrict__ out, int K)
{
  __shared__ __align__(16) u16 lA [2][BM * BK];
  __shared__ __align__(16) u16 lBg[2][BN * BK];
  __shared__ __align__(16) u16 lBl[2][BN * BK];
  const int tid = threadIdx.x;
  const int wave = tid >> 6, lane = tid & 63;
  const int quad = lane >> 4, ln = lane & 15;
  const int bid = xcd_swz_bid();
  const int bm = (bid / (int)gridDim.x) * BM, bn = (bid % (int)gridDim.x) * BN;
  const int wm = (wave >> 1) * 64, wn = (wave & 1) * 64;

  f32x4 accg[4][4] = {};
  f32x4 accl[4][4] = {};

  const int c0 = tid,       r0 = c0 >> 2, q0 = c0 & 3;
  const int c1 = tid + 256, r1 = c1 >> 2, q1 = c1 & 3;
  const u16* gA0 = A  + (size_t)(bm + r0) * K + q0 * 8;
  const u16* gA1 = A  + (size_t)(bm + r1) * K + q1 * 8;
  const u16* gG0 = Wt + (size_t)(bn + r0) * K + q0 * 8;
  const u16* gG1 = Wt + (size_t)(bn + r1) * K + q1 * 8;
  const u16* gL0 = Wt + (size_t)(DFF + bn + r0) * K + q0 * 8;
  const u16* gL1 = Wt + (size_t)(DFF + bn + r1) * K + q1 * 8;
  const int d0 = wave * 64 * 8;
  const int d1 = (256 + wave * 64) * 8;

  // prologue: stage tile 0 into buf 0
  gload16(&lA [0][d0], gA0);
  gload16(&lA [0][d1], gA1);
  gload16(&lBg[0][d0], gG0);
  gload16(&lBg[0][d1], gG1);
  gload16(&lBl[0][d0], gL0);
  gload16(&lBl[0][d1], gL1);
  __syncthreads();

  int cur = 0;
  for (int k0 = 0; k0 < K; k0 += BK) {
    const int nxt = cur ^ 1;
    if (k0 + BK < K) {
      gload16(&lA [nxt][d0], gA0 + k0 + BK);
      gload16(&lA [nxt][d1], gA1 + k0 + BK);
      gload16(&lBg[nxt][d0], gG0 + k0 + BK);
      gload16(&lBg[nxt][d1], gG1 + k0 + BK);
      gload16(&lBl[nxt][d0], gL0 + k0 + BK);
      gload16(&lBl[nxt][d1], gL1 + k0 + BK);
    }
    bf16x8 af[4], bg[4], bl[4];
#pragma unroll
    for (int i = 0; i < 4; ++i) {
      af[i] = *(const bf16x8*)&lA [cur][(wm + i * 16 + ln) * BK + quad * 8];
      bg[i] = *(const bf16x8*)&lBg[cur][(wn + i * 16 + ln) * BK + quad * 8];
      bl[i] = *(const bf16x8*)&lBl[cur][(wn + i * 16 + ln) * BK + quad * 8];
    }
#pragma unroll
    for (int i = 0; i < 4; ++i)
#pragma unroll
      for (int j = 0; j < 4; ++j) {
        accg[i][j] = __builtin_amdgcn_mfma_f32_16x16x32_bf16(af[i], bg[j], accg[i][j], 0, 0, 0);
        accl[i][j] = __builtin_amdgcn_mfma_f32_16x16x32_bf16(af[i], bl[j], accl[i][j], 0, 0, 0);
      }
    __syncthreads();
    cur = nxt;
  }

#pragma unroll
  for (int j = 0; j < 4; ++j) {
    const int col = bn + wn + j * 16 + ln;
    const float bgv = b1[col];
    const float blv = b1[DFF + col];
#pragma unroll
    for (int i = 0; i < 4; ++i) {
#pragma unroll
      for (int r = 0; r < 4; ++r) {
        const int row = bm + wm + i * 16 + quad * 4 + r;
        float gg = accg[i][j][r] + bgv;
        float ll = accl[i][j][r] + blv;
        float ge = 0.5f * gg * (1.f + erff(gg * 0.70710678118f));
        out[(size_t)row * DFF + col] = f2bf(ge * ll);
      }
    }
  }
}

// ---------------- kv = K^T @ V via MFMA (per b,h; fp32 partials) -----------
// grid: 64 bh * 4 s-chunks = 256 blocks, 256 threads (4 waves).
// Each block: M=64(d) x N=64(e) x K=1024(s) GEMM slice.
// LDS tiles [32 s][64+2] (pad=2 -> transposed frag reads ~conflict-free).
#define KVCH 1024
__global__ __launch_bounds__(256)
void kvmm_kernel(const u16* __restrict__ kk, const u16* __restrict__ vv,
                 float* __restrict__ kvpart)
{
  __shared__ __align__(16) u16 lK[32][66];
  __shared__ __align__(16) u16 lV[32][66];
  const int blk = blockIdx.x;
  const int c = blk & 3, bh = blk >> 2;
  const int b = bh >> 4, h = bh & 15;
  const int tid = threadIdx.x, wave = tid >> 6, lane = tid & 63;
  const int quad = lane >> 4, ln = lane & 15;
  const int dbase = (wave >> 1) * 32, ebase = (wave & 1) * 32;   // 32x32 quadrant
  f32x4 acc[2][2] = {};

  const int srow = tid >> 3;         // 0..31
  const int dcol = (tid & 7) * 8;    // 0..56
  const size_t gbase = ((size_t)b * SEQ + (size_t)c * KVCH + srow) * D_MODEL + h * 64 + dcol;
  const u16* gk = kk + gbase;
  const u16* gv = vv + gbase;

  for (int s0 = 0; s0 < KVCH; s0 += 32) {
    u16x8 k8 = *(const u16x8*)(gk + (size_t)s0 * D_MODEL);
    u16x8 v8 = *(const u16x8*)(gv + (size_t)s0 * D_MODEL);
    __syncthreads();
    u16x2* wk2 = (u16x2*)&lK[srow][dcol];
    u16x2* wv2 = (u16x2*)&lV[srow][dcol];
#pragma unroll
    for (int p = 0; p < 4; ++p) {
      u16x2 a; a.x = k8[2*p]; a.y = k8[2*p+1]; wk2[p] = a;
      u16x2 w; w.x = v8[2*p]; w.y = v8[2*p+1]; wv2[p] = w;
    }
    __syncthreads();
    bf16x8 af[2], bf[2];
#pragma unroll
    for (int i = 0; i < 2; ++i) {
      const int dd = dbase + i * 16 + ln;
      const int ee = ebase + i * 16 + ln;
      u16x8 at, bt;
#pragma unroll
      for (int j = 0; j < 8; ++j) {
        at[j] = lK[quad * 8 + j][dd];
        bt[j] = lV[quad * 8 + j][ee];
      }
      af[i] = __builtin_bit_cast(bf16x8, at);
      bf[i] = __builtin_bit_cast(bf16x8, bt);
    }
#pragma unroll
    for (int i = 0; i < 2; ++i)
#pragma unroll
      for (int j = 0; j < 2; ++j)
        acc[i][j] = __builtin_amdgcn_mfma_f32_16x16x32_bf16(af[i], bf[j], acc[i][j], 0, 0, 0);
  }

  float* op = kvpart + ((size_t)c * 64 + bh) * 4096;   // [c][bh][d][e]
#pragma unroll
  for (int i = 0; i < 2; ++i)
#pragma unroll
    for (int j = 0; j < 2; ++j)
#pragma unroll
      for (int r = 0; r < 4; ++r) {
        const int d = dbase + i * 16 + quad * 4 + r;
        const int e = ebase + j * 16 + ln;
        op[d * 64 + e] = acc[i][j][r];
      }
}

// sum 4 partials in place: p[i] = sum_c p[c*262144 + i]   (f32x4 vectorized)
__global__ __launch_bounds__(256)
void kvreduce_kernel(float* __restrict__ p)
{
  const int i = blockIdx.x * 256 + threadIdx.x;   // grid 256 -> 65536 f32x4
  f32x4* p4 = (f32x4*)p;
  f32x4 a = p4[i];
  f32x4 b = p4[i + 65536];
  f32x4 c = p4[i + 131072];
  f32x4 d = p4[i + 196608];
  p4[i] = (a + b) + (c + d);
}

// ---------------- attn[s,e] = sum_d q[s,d]*kv[d,e] -------------------------
__global__ __launch_bounds__(256)
void attn_kernel(const u16* __restrict__ qq, const float* __restrict__ kv,
                 u16* __restrict__ out)
{
  __shared__ __align__(16) float kvs[64 * 64];
  const int blk = blockIdx.x;          // (bh)*64 + schunk
  const int sc = blk & 63;
  const int bh = blk >> 6;
  const int b = bh >> 4, h = bh & 15;
  const int t = threadIdx.x;
  const f32x4* src = (const f32x4*)(kv + (size_t)bh * 4096);
  for (int i = t; i < 1024; i += 256) ((f32x4*)kvs)[i] = src[i];
  __syncthreads();
  const int sl = t >> 2, e0 = (t & 3) * 16;
  const size_t row = (size_t)b * SEQ + sc * 64 + sl;
  const u16* qp = qq + row * D_MODEL + h * 64;
  float qv[64];
#pragma unroll
  for (int i = 0; i < 16; ++i) {
    u16x4 u = ((const u16x4*)qp)[i];
    qv[i*4+0] = bf2f(u.x); qv[i*4+1] = bf2f(u.y);
    qv[i*4+2] = bf2f(u.z); qv[i*4+3] = bf2f(u.w);
  }
  f32x4 acc[4] = {};
  for (int d = 0; d < 64; ++d) {
    const float qd = qv[d];
    const f32x4* kr = (const f32x4*)(kvs + d * 64 + e0);
#pragma unroll
    for (int i = 0; i < 4; ++i) acc[i] += qd * kr[i];
  }
  u16* op = out + row * D_MODEL + h * 64 + e0;
#pragma unroll
  for (int i = 0; i < 4; ++i) {
    u16x4 o;
    o.x = f2bf(acc[i][0]); o.y = f2bf(acc[i][1]);
    o.z = f2bf(acc[i][2]); o.w = f2bf(acc[i][3]);
    ((u16x4*)op)[i] = o;
  }
}

// ---------------------------------------------------------------------------
// Inputs fp32, OUTPUT FP32. Workspace (peak 128 MB), lifetime-packed:
//   [0,32)MB   : transposed bf16 weights; kvpart (4MB fp32) aliases wkt+wvt
//                (both dead after K/V gemms)
//   [32,64)MB  : hb (LN1 out, bf16)  -> x1b (attn+res, bf16)
//   [64,96)MB  : kb (K) -> qb (Q) -> hb2 (LN2)
//   [96,128)MB : vb (V) -> attnb -> gbuf (FFN chunk, 32MB)
extern "C" void kernel_launch(void* const* d_in, const int* in_sizes, int n_in,
                              void* d_out, int out_size, void* d_ws, size_t ws_size,
                              hipStream_t stream)
{
  const float* x   = (const float*)d_in[0];
  const float* wq  = (const float*)d_in[1];
  const float* bq  = (const float*)d_in[2];
  const float* wk  = (const float*)d_in[3];
  const float* bk  = (const float*)d_in[4];
  const float* wv  = (const float*)d_in[5];
  const float* bv  = (const float*)d_in[6];
  const float* wo  = (const float*)d_in[7];
  const float* bo  = (const float*)d_in[8];
  const float* w1  = (const float*)d_in[9];
  const float* b1  = (const float*)d_in[10];
  const float* w2  = (const float*)d_in[11];
  const float* b2  = (const float*)d_in[12];
  const float* g1  = (const float*)d_in[13];
  const float* be1 = (const float*)d_in[14];
  const float* g2  = (const float*)d_in[15];
  const float* be2 = (const float*)d_in[16];

  char* ws = (char*)d_ws;
  const size_t MB = 1024ull * 1024ull;
  u16* wqt = (u16*)(ws + 0 * MB);
  u16* wkt = (u16*)(ws + 2 * MB);
  u16* wvt = (u16*)(ws + 4 * MB);
  u16* wot = (u16*)(ws + 6 * MB);
  u16* w1t = (u16*)(ws + 8 * MB);    // 16 MB
  u16* w2t = (u16*)(ws + 24 * MB);   // 8 MB

  u16* hb    = (u16*)(ws + 32 * MB); // LN1 out
  u16* x1b   = (u16*)(ws + 32 * MB); // alias: hb dead after Q gemm
  u16* kb    = (u16*)(ws + 64 * MB);
  u16* qb    = (u16*)(ws + 64 * MB); // alias: kb dead after kvmm_kernel
  u16* hb2   = (u16*)(ws + 64 * MB); // alias: qb dead after attn
  u16* vb    = (u16*)(ws + 96 * MB);
  u16* attnb = (u16*)(ws + 96 * MB); // alias: vb dead after kvmm_kernel
  u16* gbuf  = (u16*)(ws + 96 * MB); // alias: attnb dead after O gemm
  float* kvpart = (float*)(ws + 2 * MB); // alias wkt+wvt: dead after K/V gemms (4MB)

  // weight transposes + fp32->bf16 (N x K layout)
  transpose_kernel<<<dim3(32, 32), 256, 0, stream>>>(wq, wqt, 1024, 1024);
  transpose_kernel<<<dim3(32, 32), 256, 0, stream>>>(wk, wkt, 1024, 1024);
  transpose_kernel<<<dim3(32, 32), 256, 0, stream>>>(wv, wvt, 1024, 1024);
  transpose_kernel<<<dim3(32, 32), 256, 0, stream>>>(wo, wot, 1024, 1024);
  transpose_kernel<<<dim3(256, 32), 256, 0, stream>>>(w1, w1t, 1024, 8192);
  transpose_kernel<<<dim3(32, 128), 256, 0, stream>>>(w2, w2t, 4096, 1024);

  // LN1 (fp32 in -> bf16 out)
  ln_kernel<float><<<MROWS, 256, 0, stream>>>(x, g1, be1, hb);

  dim3 gproj(D_MODEL / BN, MROWS / BM);   // (8,128)
  // K, V first (consumed into kv), then Q overwrites kb
  gemm_kernel<1><<<gproj, 256, 0, stream>>>(hb, wkt, bk, nullptr, kb, D_MODEL, D_MODEL);
  gemm_kernel<0><<<gproj, 256, 0, stream>>>(hb, wvt, bv, nullptr, vb, D_MODEL, D_MODEL);

  // kv = K^T @ V (MFMA, 4 s-chunk partials + reduce; no atomics)
  kvmm_kernel<<<64 * 4, 256, 0, stream>>>(kb, vb, kvpart);
  kvreduce_kernel<<<256, 256, 0, stream>>>(kvpart);

  gemm_kernel<1><<<gproj, 256, 0, stream>>>(hb, wqt, bq, nullptr, qb, D_MODEL, D_MODEL);

  // attn = Q @ kv -> attnb (vb region)
  attn_kernel<<<BATCH * NHEAD * (SEQ / 64), 256, 0, stream>>>(qb, kvpart, attnb);

  // out projection + residual(x, fp32) -> x1b (hb region)
  gemm_kernel<2><<<gproj, 256, 0, stream>>>(attnb, wot, bo, x, x1b, D_MODEL, D_MODEL);

  // LN2 (bf16 in -> bf16 out) -> hb2 (qb region)
  ln_kernel<u16><<<MROWS, 256, 0, stream>>>(x1b, g2, be2, hb2);

  // FFN in row-chunks; gbuf (32 MB) reused per chunk; final out is FP32
  for (int c = 0; c < MROWS / MCHUNK; ++c) {
    const size_t ro = (size_t)c * MCHUNK;
    ffn1_kernel<<<dim3(DFF / BN, MCHUNK / BM), 256, 0, stream>>>(
        hb2 + ro * D_MODEL, w1t, b1, gbuf, D_MODEL);
    gemm_kernel<3><<<dim3(D_MODEL / BN, MCHUNK / BM), 256, 0, stream>>>(
        gbuf, w2t, b2, x1b + ro * D_MODEL, (float*)d_out + ro * D_MODEL, D_MODEL, DFF);
  }
}

// Round 6
// 1114.577 us; speedup vs baseline: 1.3913x; 1.0273x over previous
//
#include <hip/hip_runtime.h>

typedef unsigned short u16;
typedef u16  u16x2  __attribute__((ext_vector_type(2)));
typedef u16  u16x4  __attribute__((ext_vector_type(4)));
typedef u16  u16x8  __attribute__((ext_vector_type(8)));
typedef float f32x4 __attribute__((ext_vector_type(4)));
typedef __bf16 bf16x8 __attribute__((ext_vector_type(8)));

#define D_MODEL 1024
#define DFF     4096
#define SEQ     4096
#define BATCH   4
#define NHEAD   16
#define MROWS   (BATCH*SEQ)   /* 16384 */
#define MCHUNK  4096          /* FFN row-chunk (4 chunks) */

#define BM 128
#define BN 128
#define BK 32

__device__ __forceinline__ float bf2f(u16 u) {
  unsigned v = ((unsigned)u) << 16;
  return __builtin_bit_cast(float, v);
}
__device__ __forceinline__ u16 f2bf(float f) {
  unsigned u = __builtin_bit_cast(unsigned, f);
  u += 0x7fffu + ((u >> 16) & 1u);
  return (u16)(u >> 16);
}

// async global->LDS DMA, 16B per lane. LDS dest must be wave-uniform base;
// HW writes base + lane*16. Global src is per-lane.
__device__ __forceinline__ void gload16(void* lds, const void* g) {
  __builtin_amdgcn_global_load_lds(
      (const __attribute__((address_space(1))) unsigned*)g,
      (__attribute__((address_space(3))) unsigned*)lds, 16, 0, 0);
}

// raw barrier bracketed by compiler memory fences (keep ds_reads inside)
__device__ __forceinline__ void barrier_raw() {
  asm volatile("" ::: "memory");
  __builtin_amdgcn_s_barrier();
  asm volatile("" ::: "memory");
}
#define VMWAIT(n) asm volatile("s_waitcnt vmcnt(" #n ")" ::: "memory")

// T1: XCD-aware bijective block swizzle (grids here are all %8==0).
// Used ONLY for square-ish GEMMs (A-panel reuse); hurts weight-streaming ffn1.
__device__ __forceinline__ int xcd_swz_bid() {
  const int gx = gridDim.x;
  const int nwg = gx * gridDim.y;
  int bid = blockIdx.y * gx + blockIdx.x;
  const int cpx = nwg >> 3;
  return (bid & 7) * cpx + (bid >> 3);
}

// ---------------- transpose fp32 -> bf16: Wt[n][k] = bf16(W[k][n]) ---------
__global__ __launch_bounds__(256)
void transpose_kernel(const float* __restrict__ W, u16* __restrict__ Wt, int K, int N)
{
  __shared__ u16 tile[32][33];
  const int n0 = blockIdx.x * 32, k0 = blockIdx.y * 32;
  const int tx = threadIdx.x & 31, ty = threadIdx.x >> 5;   // 32 x 8
#pragma unroll
  for (int r = ty; r < 32; r += 8)
    tile[r][tx] = f2bf(W[(size_t)(k0 + r) * N + n0 + tx]);
  __syncthreads();
#pragma unroll
  for (int r = ty; r < 32; r += 8)
    Wt[(size_t)(n0 + r) * K + k0 + tx] = tile[tx][r];
}

// ---------------- LayerNorm: T in (fp32 or bf16) -> bf16 out ---------------
template<typename T>
__global__ __launch_bounds__(256)
void ln_kernel(const T* __restrict__ x, const float* __restrict__ g,
               const float* __restrict__ be, u16* __restrict__ out)
{
  const int row = blockIdx.x;
  const int t = threadIdx.x;
  float v0, v1, v2, v3;
  if constexpr (sizeof(T) == 4) {
    f32x4 u = ((const f32x4*)((const float*)x + (size_t)row * D_MODEL))[t];
    v0 = u.x; v1 = u.y; v2 = u.z; v3 = u.w;
  } else {
    u16x4 u = ((const u16x4*)((const u16*)x + (size_t)row * D_MODEL))[t];
    v0 = bf2f(u.x); v1 = bf2f(u.y); v2 = bf2f(u.z); v3 = bf2f(u.w);
  }
  float s  = v0 + v1 + v2 + v3;
  float s2 = v0*v0 + v1*v1 + v2*v2 + v3*v3;
#pragma unroll
  for (int off = 32; off > 0; off >>= 1) {
    s  += __shfl_down(s,  off);
    s2 += __shfl_down(s2, off);
  }
  __shared__ float red[8];
  if ((t & 63) == 0) { red[t >> 6] = s; red[4 + (t >> 6)] = s2; }
  __syncthreads();
  float S  = red[0] + red[1] + red[2] + red[3];
  float S2 = red[4] + red[5] + red[6] + red[7];
  float mu  = S * (1.f / D_MODEL);
  float var = S2 * (1.f / D_MODEL) - mu * mu;
  var = fmaxf(var, 0.f);
  float rs  = rsqrtf(var + 1e-5f);
  f32x4 gu = ((const f32x4*)g)[t];
  f32x4 bu = ((const f32x4*)be)[t];
  u16x4 o;
  o.x = f2bf((v0 - mu) * rs * gu.x + bu.x);
  o.y = f2bf((v1 - mu) * rs * gu.y + bu.y);
  o.z = f2bf((v2 - mu) * rs * gu.z + bu.z);
  o.w = f2bf((v3 - mu) * rs * gu.w + bu.w);
  ((u16x4*)(out + (size_t)row * D_MODEL))[t] = o;
}

// ---------------- GEMM: C = A(MxK,bf16) @ Bt(NxK,bf16)^T + bias(fp32) ------
// Counted-vmcnt pipeline (T4): 3 LDS buffers, depth-2 prefetch. Per iter:
//   issue stage(t+2) -> vmcnt(8) [stage t landed, t+1/t+2 in flight]
//   -> s_barrier -> ds_read/MFMA buf(t%3) -> s_barrier.
// No vmcnt(0) drain in the main loop. WAR safe: stage(t+2)'s buffer was last
// read at iter t-1, before the previous closing barrier.
// MODE 0: bf16 out = acc+bias
// MODE 1: bf16 out = elu(acc+bias)+1
// MODE 2: bf16 out = acc+bias + res_fp32
// MODE 3: FP32 out = acc+bias + res_bf16   (final output)
template<int MODE>
__global__ __launch_bounds__(256, 2)
void gemm_kernel(const u16* __restrict__ A, const u16* __restrict__ Bt,
                 const float* __restrict__ bias, const void* __restrict__ resv,
                 void* __restrict__ outv, int N, int K)
{
  __shared__ __align__(16) u16 lA[3][BM * BK];
  __shared__ __align__(16) u16 lB[3][BN * BK];
  const float* resf = (const float*)resv;
  const u16*   resb = (const u16*)resv;
  const int tid = threadIdx.x;
  const int wave = tid >> 6, lane = tid & 63;
  const int quad = lane >> 4, ln = lane & 15;
  const int bid = xcd_swz_bid();
  const int bm = (bid / (int)gridDim.x) * BM, bn = (bid % (int)gridDim.x) * BN;
  const int wm = (wave >> 1) * 64, wn = (wave & 1) * 64;

  f32x4 acc[4][4] = {};

  const int c0 = tid,       r0 = c0 >> 2, q0 = c0 & 3;
  const int c1 = tid + 256, r1 = c1 >> 2, q1 = c1 & 3;
  const u16* gA0 = A  + (size_t)(bm + r0) * K + q0 * 8;
  const u16* gA1 = A  + (size_t)(bm + r1) * K + q1 * 8;
  const u16* gB0 = Bt + (size_t)(bn + r0) * K + q0 * 8;
  const u16* gB1 = Bt + (size_t)(bn + r1) * K + q1 * 8;
  // per-wave-uniform LDS dest offsets (u16 units; lane*16B added by HW)
  const int d0 = wave * 64 * 8;
  const int d1 = (256 + wave * 64) * 8;

  const int nk = K / BK;
  // prologue: stages 0,1 into buffers 0,1 (8 loads in flight)
  gload16(&lA[0][d0], gA0);
  gload16(&lA[0][d1], gA1);
  gload16(&lB[0][d0], gB0);
  gload16(&lB[0][d1], gB1);
  gload16(&lA[1][d0], gA0 + BK);
  gload16(&lA[1][d1], gA1 + BK);
  gload16(&lB[1][d0], gB0 + BK);
  gload16(&lB[1][d1], gB1 + BK);

  int cur = 0;
  for (int t = 0; t < nk; ++t) {
    if (t + 2 < nk) {
      int wb = cur + 2; if (wb >= 3) wb -= 3;       // (t+2)%3
      const size_t ko = (size_t)(t + 2) * BK;
      gload16(&lA[wb][d0], gA0 + ko);
      gload16(&lA[wb][d1], gA1 + ko);
      gload16(&lB[wb][d0], gB0 + ko);
      gload16(&lB[wb][d1], gB1 + ko);
      VMWAIT(8);
    } else if (t + 1 < nk) {
      VMWAIT(4);
    } else {
      VMWAIT(0);
    }
    barrier_raw();                    // all waves' stage t complete
    bf16x8 af[4], bfr[4];
#pragma unroll
    for (int i = 0; i < 4; ++i) {
      af[i]  = *(const bf16x8*)&lA[cur][(wm + i * 16 + ln) * BK + quad * 8];
      bfr[i] = *(const bf16x8*)&lB[cur][(wn + i * 16 + ln) * BK + quad * 8];
    }
#pragma unroll
    for (int i = 0; i < 4; ++i)
#pragma unroll
      for (int j = 0; j < 4; ++j)
        acc[i][j] = __builtin_amdgcn_mfma_f32_16x16x32_bf16(af[i], bfr[j], acc[i][j], 0, 0, 0);
    barrier_raw();                    // all waves done reading buf(t%3)
    cur = cur + 1; if (cur >= 3) cur = 0;
  }

#pragma unroll
  for (int j = 0; j < 4; ++j) {
    const int col = bn + wn + j * 16 + ln;
    const float bv = bias[col];
#pragma unroll
    for (int i = 0; i < 4; ++i) {
#pragma unroll
      for (int r = 0; r < 4; ++r) {
        const int row = bm + wm + i * 16 + quad * 4 + r;
        const size_t off = (size_t)row * N + col;
        float vv = acc[i][j][r] + bv;
        if (MODE == 1) vv = vv > 0.f ? vv + 1.f : __expf(vv);
        if (MODE == 2) vv += resf[off];
        if (MODE == 3) vv += bf2f(resb[off]);
        if (MODE == 3) ((float*)outv)[off] = vv;      // final output is fp32
        else           ((u16*)outv)[off]   = f2bf(vv);
      }
    }
  }
}

// ---------------- fused FFN1: out = gelu(A@Wg + bg) * (A@Wl + bl) ----------
// Counted-vmcnt, 2 buffers (48KB LDS keeps 3 blocks/CU). No XCD swizzle
// (weight-streaming: static XCD partitions over-fetch, measured r5).
__global__ __launch_bounds__(256, 2)
void ffn1_kernel(const u16* __restrict__ A, const u16* __restrict__ Wt,
                 const float* __restrict__ b1, u16* __restrict__ out, int K)
{
  __shared__ __align__(16) u16 lA [2][BM * BK];
  __shared__ __align__(16) u16 lBg[2][BN * BK];
  __shared__ __align__(16) u16 lBl[2][BN * BK];
  const int tid = threadIdx.x;
  const int wave = tid >> 6, lane = tid & 63;
  const int quad = lane >> 4, ln = lane & 15;
  const int bm = blockIdx.y * BM, bn = blockIdx.x * BN;
  const int wm = (wave >> 1) * 64, wn = (wave & 1) * 64;

  f32x4 accg[4][4] = {};
  f32x4 accl[4][4] = {};

  const int c0 = tid,       r0 = c0 >> 2, q0 = c0 & 3;
  const int c1 = tid + 256, r1 = c1 >> 2, q1 = c1 & 3;
  const u16* gA0 = A  + (size_t)(bm + r0) * K + q0 * 8;
  const u16* gA1 = A  + (size_t)(bm + r1) * K + q1 * 8;
  const u16* gG0 = Wt + (size_t)(bn + r0) * K + q0 * 8;
  const u16* gG1 = Wt + (size_t)(bn + r1) * K + q1 * 8;
  const u16* gL0 = Wt + (size_t)(DFF + bn + r0) * K + q0 * 8;
  const u16* gL1 = Wt + (size_t)(DFF + bn + r1) * K + q1 * 8;
  const int d0 = wave * 64 * 8;
  const int d1 = (256 + wave * 64) * 8;

  const int nk = K / BK;
  // prologue: stage 0 into buf 0 (6 loads)
  gload16(&lA [0][d0], gA0);
  gload16(&lA [0][d1], gA1);
  gload16(&lBg[0][d0], gG0);
  gload16(&lBg[0][d1], gG1);
  gload16(&lBl[0][d0], gL0);
  gload16(&lBl[0][d1], gL1);

  int cur = 0;
  for (int t = 0; t < nk; ++t) {
    if (t + 1 < nk) {
      const int nxt = cur ^ 1;
      const size_t ko = (size_t)(t + 1) * BK;
      gload16(&lA [nxt][d0], gA0 + ko);
      gload16(&lA [nxt][d1], gA1 + ko);
      gload16(&lBg[nxt][d0], gG0 + ko);
      gload16(&lBg[nxt][d1], gG1 + ko);
      gload16(&lBl[nxt][d0], gL0 + ko);
      gload16(&lBl[nxt][d1], gL1 + ko);
      VMWAIT(6);                      // stage t landed; t+1 stays in flight
    } else {
      VMWAIT(0);
    }
    barrier_raw();
    bf16x8 af[4], bg[4], bl[4];
#pragma unroll
    for (int i = 0; i < 4; ++i) {
      af[i] = *(const bf16x8*)&lA [cur][(wm + i * 16 + ln) * BK + quad * 8];
      bg[i] = *(const bf16x8*)&lBg[cur][(wn + i * 16 + ln) * BK + quad * 8];
      bl[i] = *(const bf16x8*)&lBl[cur][(wn + i * 16 + ln) * BK + quad * 8];
    }
#pragma unroll
    for (int i = 0; i < 4; ++i)
#pragma unroll
      for (int j = 0; j < 4; ++j) {
        accg[i][j] = __builtin_amdgcn_mfma_f32_16x16x32_bf16(af[i], bg[j], accg[i][j], 0, 0, 0);
        accl[i][j] = __builtin_amdgcn_mfma_f32_16x16x32_bf16(af[i], bl[j], accl[i][j], 0, 0, 0);
      }
    barrier_raw();
    cur ^= 1;
  }

#pragma unroll
  for (int j = 0; j < 4; ++j) {
    const int col = bn + wn + j * 16 + ln;
    const float bgv = b1[col];
    const float blv = b1[DFF + col];
#pragma unroll
    for (int i = 0; i < 4; ++i) {
#pragma unroll
      for (int r = 0; r < 4; ++r) {
        const int row = bm + wm + i * 16 + quad * 4 + r;
        float gg = accg[i][j][r] + bgv;
        float ll = accl[i][j][r] + blv;
        float ge = 0.5f * gg * (1.f + erff(gg * 0.70710678118f));
        out[(size_t)row * DFF + col] = f2bf(ge * ll);
      }
    }
  }
}

// ---------------- kv = K^T @ V via MFMA (per b,h; fp32 partials) -----------
// grid: 64 bh * 4 s-chunks = 256 blocks, 256 threads (4 waves).
// Each block: M=64(d) x N=64(e) x K=1024(s) GEMM slice.
// LDS tiles [32 s][64+2] (pad=2 -> transposed frag reads ~conflict-free).
#define KVCH 1024
__global__ __launch_bounds__(256)
void kvmm_kernel(const u16* __restrict__ kk, const u16* __restrict__ vv,
                 float* __restrict__ kvpart)
{
  __shared__ __align__(16) u16 lK[32][66];
  __shared__ __align__(16) u16 lV[32][66];
  const int blk = blockIdx.x;
  const int c = blk & 3, bh = blk >> 2;
  const int b = bh >> 4, h = bh & 15;
  const int tid = threadIdx.x, wave = tid >> 6, lane = tid & 63;
  const int quad = lane >> 4, ln = lane & 15;
  const int dbase = (wave >> 1) * 32, ebase = (wave & 1) * 32;   // 32x32 quadrant
  f32x4 acc[2][2] = {};

  const int srow = tid >> 3;         // 0..31
  const int dcol = (tid & 7) * 8;    // 0..56
  const size_t gbase = ((size_t)b * SEQ + (size_t)c * KVCH + srow) * D_MODEL + h * 64 + dcol;
  const u16* gk = kk + gbase;
  const u16* gv = vv + gbase;

  for (int s0 = 0; s0 < KVCH; s0 += 32) {
    u16x8 k8 = *(const u16x8*)(gk + (size_t)s0 * D_MODEL);
    u16x8 v8 = *(const u16x8*)(gv + (size_t)s0 * D_MODEL);
    __syncthreads();
    u16x2* wk2 = (u16x2*)&lK[srow][dcol];
    u16x2* wv2 = (u16x2*)&lV[srow][dcol];
#pragma unroll
    for (int p = 0; p < 4; ++p) {
      u16x2 a; a.x = k8[2*p]; a.y = k8[2*p+1]; wk2[p] = a;
      u16x2 w; w.x = v8[2*p]; w.y = v8[2*p+1]; wv2[p] = w;
    }
    __syncthreads();
    bf16x8 af[2], bf[2];
#pragma unroll
    for (int i = 0; i < 2; ++i) {
      const int dd = dbase + i * 16 + ln;
      const int ee = ebase + i * 16 + ln;
      u16x8 at, bt;
#pragma unroll
      for (int j = 0; j < 8; ++j) {
        at[j] = lK[quad * 8 + j][dd];
        bt[j] = lV[quad * 8 + j][ee];
      }
      af[i] = __builtin_bit_cast(bf16x8, at);
      bf[i] = __builtin_bit_cast(bf16x8, bt);
    }
#pragma unroll
    for (int i = 0; i < 2; ++i)
#pragma unroll
      for (int j = 0; j < 2; ++j)
        acc[i][j] = __builtin_amdgcn_mfma_f32_16x16x32_bf16(af[i], bf[j], acc[i][j], 0, 0, 0);
  }

  float* op = kvpart + ((size_t)c * 64 + bh) * 4096;   // [c][bh][d][e]
#pragma unroll
  for (int i = 0; i < 2; ++i)
#pragma unroll
    for (int j = 0; j < 2; ++j)
#pragma unroll
      for (int r = 0; r < 4; ++r) {
        const int d = dbase + i * 16 + quad * 4 + r;
        const int e = ebase + j * 16 + ln;
        op[d * 64 + e] = acc[i][j][r];
      }
}

// sum 4 partials in place: p[i] = sum_c p[c*262144 + i]   (f32x4 vectorized)
__global__ __launch_bounds__(256)
void kvreduce_kernel(float* __restrict__ p)
{
  const int i = blockIdx.x * 256 + threadIdx.x;   // grid 256 -> 65536 f32x4
  f32x4* p4 = (f32x4*)p;
  f32x4 a = p4[i];
  f32x4 b = p4[i + 65536];
  f32x4 c = p4[i + 131072];
  f32x4 d = p4[i + 196608];
  p4[i] = (a + b) + (c + d);
}

// ---------------- attn[s,e] = sum_d q[s,d]*kv[d,e] -------------------------
__global__ __launch_bounds__(256)
void attn_kernel(const u16* __restrict__ qq, const float* __restrict__ kv,
                 u16* __restrict__ out)
{
  __shared__ __align__(16) float kvs[64 * 64];
  const int blk = blockIdx.x;          // (bh)*64 + schunk
  const int sc = blk & 63;
  const int bh = blk >> 6;
  const int b = bh >> 4, h = bh & 15;
  const int t = threadIdx.x;
  const f32x4* src = (const f32x4*)(kv + (size_t)bh * 4096);
  for (int i = t; i < 1024; i += 256) ((f32x4*)kvs)[i] = src[i];
  __syncthreads();
  const int sl = t >> 2, e0 = (t & 3) * 16;
  const size_t row = (size_t)b * SEQ + sc * 64 + sl;
  const u16* qp = qq + row * D_MODEL + h * 64;
  float qv[64];
#pragma unroll
  for (int i = 0; i < 16; ++i) {
    u16x4 u = ((const u16x4*)qp)[i];
    qv[i*4+0] = bf2f(u.x); qv[i*4+1] = bf2f(u.y);
    qv[i*4+2] = bf2f(u.z); qv[i*4+3] = bf2f(u.w);
  }
  f32x4 acc[4] = {};
  for (int d = 0; d < 64; ++d) {
    const float qd = qv[d];
    const f32x4* kr = (const f32x4*)(kvs + d * 64 + e0);
#pragma unroll
    for (int i = 0; i < 4; ++i) acc[i] += qd * kr[i];
  }
  u16* op = out + row * D_MODEL + h * 64 + e0;
#pragma unroll
  for (int i = 0; i < 4; ++i) {
    u16x4 o;
    o.x = f2bf(acc[i][0]); o.y = f2bf(acc[i][1]);
    o.z = f2bf(acc[i][2]); o.w = f2bf(acc[i][3]);
    ((u16x4*)op)[i] = o;
  }
}

// ---------------------------------------------------------------------------
// Inputs fp32, OUTPUT FP32. Workspace (peak 128 MB), lifetime-packed:
//   [0,32)MB   : transposed bf16 weights; kvpart (4MB fp32) aliases wkt+wvt
//                (both dead after K/V gemms)
//   [32,64)MB  : hb (LN1 out, bf16)  -> x1b (attn+res, bf16)
//   [64,96)MB  : kb (K) -> qb (Q) -> hb2 (LN2)
//   [96,128)MB : vb (V) -> attnb -> gbuf (FFN chunk, 32MB)
extern "C" void kernel_launch(void* const* d_in, const int* in_sizes, int n_in,
                              void* d_out, int out_size, void* d_ws, size_t ws_size,
                              hipStream_t stream)
{
  const float* x   = (const float*)d_in[0];
  const float* wq  = (const float*)d_in[1];
  const float* bq  = (const float*)d_in[2];
  const float* wk  = (const float*)d_in[3];
  const float* bk  = (const float*)d_in[4];
  const float* wv  = (const float*)d_in[5];
  const float* bv  = (const float*)d_in[6];
  const float* wo  = (const float*)d_in[7];
  const float* bo  = (const float*)d_in[8];
  const float* w1  = (const float*)d_in[9];
  const float* b1  = (const float*)d_in[10];
  const float* w2  = (const float*)d_in[11];
  const float* b2  = (const float*)d_in[12];
  const float* g1  = (const float*)d_in[13];
  const float* be1 = (const float*)d_in[14];
  const float* g2  = (const float*)d_in[15];
  const float* be2 = (const float*)d_in[16];

  char* ws = (char*)d_ws;
  const size_t MB = 1024ull * 1024ull;
  u16* wqt = (u16*)(ws + 0 * MB);
  u16* wkt = (u16*)(ws + 2 * MB);
  u16* wvt = (u16*)(ws + 4 * MB);
  u16* wot = (u16*)(ws + 6 * MB);
  u16* w1t = (u16*)(ws + 8 * MB);    // 16 MB
  u16* w2t = (u16*)(ws + 24 * MB);   // 8 MB

  u16* hb    = (u16*)(ws + 32 * MB); // LN1 out
  u16* x1b   = (u16*)(ws + 32 * MB); // alias: hb dead after Q gemm
  u16* kb    = (u16*)(ws + 64 * MB);
  u16* qb    = (u16*)(ws + 64 * MB); // alias: kb dead after kvmm_kernel
  u16* hb2   = (u16*)(ws + 64 * MB); // alias: qb dead after attn
  u16* vb    = (u16*)(ws + 96 * MB);
  u16* attnb = (u16*)(ws + 96 * MB); // alias: vb dead after kvmm_kernel
  u16* gbuf  = (u16*)(ws + 96 * MB); // alias: attnb dead after O gemm
  float* kvpart = (float*)(ws + 2 * MB); // alias wkt+wvt: dead after K/V gemms (4MB)

  // weight transposes + fp32->bf16 (N x K layout)
  transpose_kernel<<<dim3(32, 32), 256, 0, stream>>>(wq, wqt, 1024, 1024);
  transpose_kernel<<<dim3(32, 32), 256, 0, stream>>>(wk, wkt, 1024, 1024);
  transpose_kernel<<<dim3(32, 32), 256, 0, stream>>>(wv, wvt, 1024, 1024);
  transpose_kernel<<<dim3(32, 32), 256, 0, stream>>>(wo, wot, 1024, 1024);
  transpose_kernel<<<dim3(256, 32), 256, 0, stream>>>(w1, w1t, 1024, 8192);
  transpose_kernel<<<dim3(32, 128), 256, 0, stream>>>(w2, w2t, 4096, 1024);

  // LN1 (fp32 in -> bf16 out)
  ln_kernel<float><<<MROWS, 256, 0, stream>>>(x, g1, be1, hb);

  dim3 gproj(D_MODEL / BN, MROWS / BM);   // (8,128)
  // K, V first (consumed into kv), then Q overwrites kb
  gemm_kernel<1><<<gproj, 256, 0, stream>>>(hb, wkt, bk, nullptr, kb, D_MODEL, D_MODEL);
  gemm_kernel<0><<<gproj, 256, 0, stream>>>(hb, wvt, bv, nullptr, vb, D_MODEL, D_MODEL);

  // kv = K^T @ V (MFMA, 4 s-chunk partials + reduce; no atomics)
  kvmm_kernel<<<64 * 4, 256, 0, stream>>>(kb, vb, kvpart);
  kvreduce_kernel<<<256, 256, 0, stream>>>(kvpart);

  gemm_kernel<1><<<gproj, 256, 0, stream>>>(hb, wqt, bq, nullptr, qb, D_MODEL, D_MODEL);

  // attn = Q @ kv -> attnb (vb region)
  attn_kernel<<<BATCH * NHEAD * (SEQ / 64), 256, 0, stream>>>(qb, kvpart, attnb);

  // out projection + residual(x, fp32) -> x1b (hb region)
  gemm_kernel<2><<<gproj, 256, 0, stream>>>(attnb, wot, bo, x, x1b, D_MODEL, D_MODEL);

  // LN2 (bf16 in -> bf16 out) -> hb2 (qb region)
  ln_kernel<u16><<<MROWS, 256, 0, stream>>>(x1b, g2, be2, hb2);

  // FFN in row-chunks; gbuf (32 MB) reused per chunk; final out is FP32
  for (int c = 0; c < MROWS / MCHUNK; ++c) {
    const size_t ro = (size_t)c * MCHUNK;
    ffn1_kernel<<<dim3(DFF / BN, MCHUNK / BM), 256, 0, stream>>>(
        hb2 + ro * D_MODEL, w1t, b1, gbuf, D_MODEL);
    gemm_kernel<3><<<dim3(D_MODEL / BN, MCHUNK / BM), 256, 0, stream>>>(
        gbuf, w2t, b2, x1b + ro * D_MODEL, (float*)d_out + ro * D_MODEL, D_MODEL, DFF);
  }
}

// Round 7
// 1014.547 us; speedup vs baseline: 1.5284x; 1.0986x over previous
//
#include <hip/hip_runtime.h>

typedef unsigned short u16;
typedef u16  u16x2  __attribute__((ext_vector_type(2)));
typedef u16  u16x4  __attribute__((ext_vector_type(4)));
typedef u16  u16x8  __attribute__((ext_vector_type(8)));
typedef float f32x4 __attribute__((ext_vector_type(4)));
typedef __bf16 bf16x8 __attribute__((ext_vector_type(8)));

#define D_MODEL 1024
#define DFF     4096
#define SEQ     4096
#define BATCH   4
#define NHEAD   16
#define MROWS   (BATCH*SEQ)   /* 16384 */
#define MCHUNK  4096          /* FFN row-chunk (4 chunks) */

#define BM 128
#define BK 32

__device__ __forceinline__ float bf2f(u16 u) {
  unsigned v = ((unsigned)u) << 16;
  return __builtin_bit_cast(float, v);
}
__device__ __forceinline__ u16 f2bf(float f) {
  unsigned u = __builtin_bit_cast(unsigned, f);
  u += 0x7fffu + ((u >> 16) & 1u);
  return (u16)(u >> 16);
}

// async global->LDS DMA, 16B per lane. LDS dest must be wave-uniform base;
// HW writes base + lane*16. Global src is per-lane.
__device__ __forceinline__ void gload16(void* lds, const void* g) {
  __builtin_amdgcn_global_load_lds(
      (const __attribute__((address_space(1))) unsigned*)g,
      (__attribute__((address_space(3))) unsigned*)lds, 16, 0, 0);
}

// raw barrier bracketed by compiler memory fences (keep ds_reads inside)
__device__ __forceinline__ void barrier_raw() {
  asm volatile("" ::: "memory");
  __builtin_amdgcn_s_barrier();
  asm volatile("" ::: "memory");
}
#define VMWAIT(n) asm volatile("s_waitcnt vmcnt(" #n ")" ::: "memory")

// T1: XCD-aware bijective block swizzle (grids here are all %8==0).
// Used ONLY for gemm_kernel (A-panel reuse); hurts weight-streaming ffn1.
__device__ __forceinline__ int xcd_swz_bid() {
  const int gx = gridDim.x;
  const int nwg = gx * gridDim.y;
  int bid = blockIdx.y * gx + blockIdx.x;
  const int cpx = nwg >> 3;
  return (bid & 7) * cpx + (bid >> 3);
}

// ---------------- transpose fp32 -> bf16: Wt[n][k] = bf16(W[k][n]) ---------
__global__ __launch_bounds__(256)
void transpose_kernel(const float* __restrict__ W, u16* __restrict__ Wt, int K, int N)
{
  __shared__ u16 tile[32][33];
  const int n0 = blockIdx.x * 32, k0 = blockIdx.y * 32;
  const int tx = threadIdx.x & 31, ty = threadIdx.x >> 5;   // 32 x 8
#pragma unroll
  for (int r = ty; r < 32; r += 8)
    tile[r][tx] = f2bf(W[(size_t)(k0 + r) * N + n0 + tx]);
  __syncthreads();
#pragma unroll
  for (int r = ty; r < 32; r += 8)
    Wt[(size_t)(n0 + r) * K + k0 + tx] = tile[tx][r];
}

// ---------------- LayerNorm: T in (fp32 or bf16) -> bf16 out ---------------
template<typename T>
__global__ __launch_bounds__(256)
void ln_kernel(const T* __restrict__ x, const float* __restrict__ g,
               const float* __restrict__ be, u16* __restrict__ out)
{
  const int row = blockIdx.x;
  const int t = threadIdx.x;
  float v0, v1, v2, v3;
  if constexpr (sizeof(T) == 4) {
    f32x4 u = ((const f32x4*)((const float*)x + (size_t)row * D_MODEL))[t];
    v0 = u.x; v1 = u.y; v2 = u.z; v3 = u.w;
  } else {
    u16x4 u = ((const u16x4*)((const u16*)x + (size_t)row * D_MODEL))[t];
    v0 = bf2f(u.x); v1 = bf2f(u.y); v2 = bf2f(u.z); v3 = bf2f(u.w);
  }
  float s  = v0 + v1 + v2 + v3;
  float s2 = v0*v0 + v1*v1 + v2*v2 + v3*v3;
#pragma unroll
  for (int off = 32; off > 0; off >>= 1) {
    s  += __shfl_down(s,  off);
    s2 += __shfl_down(s2, off);
  }
  __shared__ float red[8];
  if ((t & 63) == 0) { red[t >> 6] = s; red[4 + (t >> 6)] = s2; }
  __syncthreads();
  float S  = red[0] + red[1] + red[2] + red[3];
  float S2 = red[4] + red[5] + red[6] + red[7];
  float mu  = S * (1.f / D_MODEL);
  float var = S2 * (1.f / D_MODEL) - mu * mu;
  var = fmaxf(var, 0.f);
  float rs  = rsqrtf(var + 1e-5f);
  f32x4 gu = ((const f32x4*)g)[t];
  f32x4 bu = ((const f32x4*)be)[t];
  u16x4 o;
  o.x = f2bf((v0 - mu) * rs * gu.x + bu.x);
  o.y = f2bf((v1 - mu) * rs * gu.y + bu.y);
  o.z = f2bf((v2 - mu) * rs * gu.z + bu.z);
  o.w = f2bf((v3 - mu) * rs * gu.w + bu.w);
  ((u16x4*)(out + (size_t)row * D_MODEL))[t] = o;
}

// ---------------- GEMM: C = A(MxK,bf16) @ Bt(NxK,bf16)^T + bias(fp32) ------
// Dual-K-step counted pipeline: 4 LDS buffers; each iteration computes TWO
// BK=32 steps (32 MFMA at BNT=128) inside ONE barrier pair, prefetching the
// next two steps with counted vmcnt (never 0 mid-loop). Halves barrier
// frequency per FLOP vs the classic 2-barrier/step frame.
// BNT=64 variant: half-width B tile -> 2x grid for skinny-N shapes (FFN2).
// MODE 0: bf16 out = acc+bias
// MODE 1: bf16 out = elu(acc+bias)+1
// MODE 2: bf16 out = acc+bias + res_fp32
// MODE 3: FP32 out = acc+bias + res_bf16   (final output)
template<int MODE, int BNT>
__global__ __launch_bounds__(256, 2)
void gemm_kernel(const u16* __restrict__ A, const u16* __restrict__ Bt,
                 const float* __restrict__ bias, const void* __restrict__ resv,
                 void* __restrict__ outv, int N, int K)
{
  constexpr int NJ = BNT / 32;                  // B frags per wave
  __shared__ __align__(16) u16 lA[4][BM * BK];
  __shared__ __align__(16) u16 lB[4][BNT * BK];
  const float* resf = (const float*)resv;
  const u16*   resb = (const u16*)resv;
  const int tid = threadIdx.x;
  const int wave = tid >> 6, lane = tid & 63;
  const int quad = lane >> 4, ln = lane & 15;
  const int bid = xcd_swz_bid();
  const int bm = (bid / (int)gridDim.x) * BM, bn = (bid % (int)gridDim.x) * BNT;
  const int wm = (wave >> 1) * 64, wn = (wave & 1) * (BNT / 2);

  f32x4 acc[4][NJ] = {};

  const int c0 = tid,       r0 = c0 >> 2, q0 = c0 & 3;
  const int c1 = tid + 256, r1 = c1 >> 2, q1 = c1 & 3;
  const u16* gA0 = A  + (size_t)(bm + r0) * K + q0 * 8;
  const u16* gA1 = A  + (size_t)(bm + r1) * K + q1 * 8;
  const u16* gB0 = Bt + (size_t)(bn + r0) * K + q0 * 8;
  const u16* gB1 = Bt + (size_t)(bn + r1) * K + q1 * 8;
  // per-wave-uniform LDS dest offsets (u16 units; lane*16B added by HW)
  const int d0 = wave * 64 * 8;
  const int d1 = (256 + wave * 64) * 8;

  auto stage = [&](int b, size_t ko) {
    gload16(&lA[b][d0], gA0 + ko);
    gload16(&lA[b][d1], gA1 + ko);
    gload16(&lB[b][d0], gB0 + ko);
    if constexpr (BNT == 128) gload16(&lB[b][d1], gB1 + ko);
  };
  auto compute = [&](int b) {
    bf16x8 af[4], bfr[NJ];
#pragma unroll
    for (int i = 0; i < 4; ++i)
      af[i] = *(const bf16x8*)&lA[b][(wm + i * 16 + ln) * BK + quad * 8];
#pragma unroll
    for (int j = 0; j < NJ; ++j)
      bfr[j] = *(const bf16x8*)&lB[b][(wn + j * 16 + ln) * BK + quad * 8];
#pragma unroll
    for (int i = 0; i < 4; ++i)
#pragma unroll
      for (int j = 0; j < NJ; ++j)
        acc[i][j] = __builtin_amdgcn_mfma_f32_16x16x32_bf16(af[i], bfr[j], acc[i][j], 0, 0, 0);
  };

  const int ni = K / 64;                        // dual-step iterations
  stage(0, 0);
  stage(1, BK);

  for (int i = 0; i < ni; ++i) {
    const int b0 = (i & 1) * 2, b1 = b0 + 1;    // bufs for steps 2i, 2i+1
    if (i + 1 < ni) {
      const size_t ko = (size_t)(i + 1) * 64;
      stage(b0 ^ 2, ko);                        // steps 2i+2, 2i+3
      stage(b1 ^ 2, ko + BK);
      if constexpr (BNT == 128) { VMWAIT(8); } else { VMWAIT(6); }
    } else {
      VMWAIT(0);
    }
    barrier_raw();                              // steps 2i,2i+1 resident
    compute(b0);
    compute(b1);
    barrier_raw();                              // all waves done with b0,b1
  }

#pragma unroll
  for (int j = 0; j < NJ; ++j) {
    const int col = bn + wn + j * 16 + ln;
    const float bv = bias[col];
#pragma unroll
    for (int i = 0; i < 4; ++i) {
#pragma unroll
      for (int r = 0; r < 4; ++r) {
        const int row = bm + wm + i * 16 + quad * 4 + r;
        const size_t off = (size_t)row * N + col;
        float vv = acc[i][j][r] + bv;
        if (MODE == 1) vv = vv > 0.f ? vv + 1.f : __expf(vv);
        if (MODE == 2) vv += resf[off];
        if (MODE == 3) vv += bf2f(resb[off]);
        if (MODE == 3) ((float*)outv)[off] = vv;      // final output is fp32
        else           ((u16*)outv)[off]   = f2bf(vv);
      }
    }
  }
}

// ---------------- fused FFN1: out = gelu(A@Wg + bg) * (A@Wl + bl) ----------
// Counted-vmcnt, 2 buffers (48KB LDS). No XCD swizzle (weight-streaming:
// static XCD partitions over-fetch, measured r5). 32 MFMA per barrier pair.
__global__ __launch_bounds__(256, 2)
void ffn1_kernel(const u16* __restrict__ A, const u16* __restrict__ Wt,
                 const float* __restrict__ b1, u16* __restrict__ out, int K)
{
  __shared__ __align__(16) u16 lA [2][BM * BK];
  __shared__ __align__(16) u16 lBg[2][BM * BK];
  __shared__ __align__(16) u16 lBl[2][BM * BK];
  const int tid = threadIdx.x;
  const int wave = tid >> 6, lane = tid & 63;
  const int quad = lane >> 4, ln = lane & 15;
  const int bm = blockIdx.y * BM, bn = blockIdx.x * BM;
  const int wm = (wave >> 1) * 64, wn = (wave & 1) * 64;

  f32x4 accg[4][4] = {};
  f32x4 accl[4][4] = {};

  const int c0 = tid,       r0 = c0 >> 2, q0 = c0 & 3;
  const int c1 = tid + 256, r1 = c1 >> 2, q1 = c1 & 3;
  const u16* gA0 = A  + (size_t)(bm + r0) * K + q0 * 8;
  const u16* gA1 = A  + (size_t)(bm + r1) * K + q1 * 8;
  const u16* gG0 = Wt + (size_t)(bn + r0) * K + q0 * 8;
  const u16* gG1 = Wt + (size_t)(bn + r1) * K + q1 * 8;
  const u16* gL0 = Wt + (size_t)(DFF + bn + r0) * K + q0 * 8;
  const u16* gL1 = Wt + (size_t)(DFF + bn + r1) * K + q1 * 8;
  const int d0 = wave * 64 * 8;
  const int d1 = (256 + wave * 64) * 8;

  const int nk = K / BK;
  // prologue: stage 0 into buf 0 (6 loads)
  gload16(&lA [0][d0], gA0);
  gload16(&lA [0][d1], gA1);
  gload16(&lBg[0][d0], gG0);
  gload16(&lBg[0][d1], gG1);
  gload16(&lBl[0][d0], gL0);
  gload16(&lBl[0][d1], gL1);

  int cur = 0;
  for (int t = 0; t < nk; ++t) {
    if (t + 1 < nk) {
      const int nxt = cur ^ 1;
      const size_t ko = (size_t)(t + 1) * BK;
      gload16(&lA [nxt][d0], gA0 + ko);
      gload16(&lA [nxt][d1], gA1 + ko);
      gload16(&lBg[nxt][d0], gG0 + ko);
      gload16(&lBg[nxt][d1], gG1 + ko);
      gload16(&lBl[nxt][d0], gL0 + ko);
      gload16(&lBl[nxt][d1], gL1 + ko);
      VMWAIT(6);                      // stage t landed; t+1 stays in flight
    } else {
      VMWAIT(0);
    }
    barrier_raw();
    bf16x8 af[4], bg[4], bl[4];
#pragma unroll
    for (int i = 0; i < 4; ++i) {
      af[i] = *(const bf16x8*)&lA [cur][(wm + i * 16 + ln) * BK + quad * 8];
      bg[i] = *(const bf16x8*)&lBg[cur][(wn + i * 16 + ln) * BK + quad * 8];
      bl[i] = *(const bf16x8*)&lBl[cur][(wn + i * 16 + ln) * BK + quad * 8];
    }
#pragma unroll
    for (int i = 0; i < 4; ++i)
#pragma unroll
      for (int j = 0; j < 4; ++j) {
        accg[i][j] = __builtin_amdgcn_mfma_f32_16x16x32_bf16(af[i], bg[j], accg[i][j], 0, 0, 0);
        accl[i][j] = __builtin_amdgcn_mfma_f32_16x16x32_bf16(af[i], bl[j], accl[i][j], 0, 0, 0);
      }
    barrier_raw();
    cur ^= 1;
  }

#pragma unroll
  for (int j = 0; j < 4; ++j) {
    const int col = bn + wn + j * 16 + ln;
    const float bgv = b1[col];
    const float blv = b1[DFF + col];
#pragma unroll
    for (int i = 0; i < 4; ++i) {
#pragma unroll
      for (int r = 0; r < 4; ++r) {
        const int row = bm + wm + i * 16 + quad * 4 + r;
        float gg = accg[i][j][r] + bgv;
        float ll = accl[i][j][r] + blv;
        float ge = 0.5f * gg * (1.f + erff(gg * 0.70710678118f));
        out[(size_t)row * DFF + col] = f2bf(ge * ll);
      }
    }
  }
}

// ---------------- kv = K^T @ V via MFMA (per b,h; fp32 partials) -----------
#define KVCH 1024
__global__ __launch_bounds__(256)
void kvmm_kernel(const u16* __restrict__ kk, const u16* __restrict__ vv,
                 float* __restrict__ kvpart)
{
  __shared__ __align__(16) u16 lK[32][66];
  __shared__ __align__(16) u16 lV[32][66];
  const int blk = blockIdx.x;
  const int c = blk & 3, bh = blk >> 2;
  const int b = bh >> 4, h = bh & 15;
  const int tid = threadIdx.x, wave = tid >> 6, lane = tid & 63;
  const int quad = lane >> 4, ln = lane & 15;
  const int dbase = (wave >> 1) * 32, ebase = (wave & 1) * 32;   // 32x32 quadrant
  f32x4 acc[2][2] = {};

  const int srow = tid >> 3;         // 0..31
  const int dcol = (tid & 7) * 8;    // 0..56
  const size_t gbase = ((size_t)b * SEQ + (size_t)c * KVCH + srow) * D_MODEL + h * 64 + dcol;
  const u16* gk = kk + gbase;
  const u16* gv = vv + gbase;

  for (int s0 = 0; s0 < KVCH; s0 += 32) {
    u16x8 k8 = *(const u16x8*)(gk + (size_t)s0 * D_MODEL);
    u16x8 v8 = *(const u16x8*)(gv + (size_t)s0 * D_MODEL);
    __syncthreads();
    u16x2* wk2 = (u16x2*)&lK[srow][dcol];
    u16x2* wv2 = (u16x2*)&lV[srow][dcol];
#pragma unroll
    for (int p = 0; p < 4; ++p) {
      u16x2 a; a.x = k8[2*p]; a.y = k8[2*p+1]; wk2[p] = a;
      u16x2 w; w.x = v8[2*p]; w.y = v8[2*p+1]; wv2[p] = w;
    }
    __syncthreads();
    bf16x8 af[2], bf[2];
#pragma unroll
    for (int i = 0; i < 2; ++i) {
      const int dd = dbase + i * 16 + ln;
      const int ee = ebase + i * 16 + ln;
      u16x8 at, bt;
#pragma unroll
      for (int j = 0; j < 8; ++j) {
        at[j] = lK[quad * 8 + j][dd];
        bt[j] = lV[quad * 8 + j][ee];
      }
      af[i] = __builtin_bit_cast(bf16x8, at);
      bf[i] = __builtin_bit_cast(bf16x8, bt);
    }
#pragma unroll
    for (int i = 0; i < 2; ++i)
#pragma unroll
      for (int j = 0; j < 2; ++j)
        acc[i][j] = __builtin_amdgcn_mfma_f32_16x16x32_bf16(af[i], bf[j], acc[i][j], 0, 0, 0);
  }

  float* op = kvpart + ((size_t)c * 64 + bh) * 4096;   // [c][bh][d][e]
#pragma unroll
  for (int i = 0; i < 2; ++i)
#pragma unroll
    for (int j = 0; j < 2; ++j)
#pragma unroll
      for (int r = 0; r < 4; ++r) {
        const int d = dbase + i * 16 + quad * 4 + r;
        const int e = ebase + j * 16 + ln;
        op[d * 64 + e] = acc[i][j][r];
      }
}

// sum 4 partials in place: p[i] = sum_c p[c*262144 + i]   (f32x4 vectorized)
__global__ __launch_bounds__(256)
void kvreduce_kernel(float* __restrict__ p)
{
  const int i = blockIdx.x * 256 + threadIdx.x;   // grid 256 -> 65536 f32x4
  f32x4* p4 = (f32x4*)p;
  f32x4 a = p4[i];
  f32x4 b = p4[i + 65536];
  f32x4 c = p4[i + 131072];
  f32x4 d = p4[i + 196608];
  p4[i] = (a + b) + (c + d);
}

// ---------------- attn[s,e] = sum_d q[s,d]*kv[d,e] -------------------------
__global__ __launch_bounds__(256)
void attn_kernel(const u16* __restrict__ qq, const float* __restrict__ kv,
                 u16* __restrict__ out)
{
  __shared__ __align__(16) float kvs[64 * 64];
  const int blk = blockIdx.x;          // (bh)*64 + schunk
  const int sc = blk & 63;
  const int bh = blk >> 6;
  const int b = bh >> 4, h = bh & 15;
  const int t = threadIdx.x;
  const f32x4* src = (const f32x4*)(kv + (size_t)bh * 4096);
  for (int i = t; i < 1024; i += 256) ((f32x4*)kvs)[i] = src[i];
  __syncthreads();
  const int sl = t >> 2, e0 = (t & 3) * 16;
  const size_t row = (size_t)b * SEQ + sc * 64 + sl;
  const u16* qp = qq + row * D_MODEL + h * 64;
  float qv[64];
#pragma unroll
  for (int i = 0; i < 16; ++i) {
    u16x4 u = ((const u16x4*)qp)[i];
    qv[i*4+0] = bf2f(u.x); qv[i*4+1] = bf2f(u.y);
    qv[i*4+2] = bf2f(u.z); qv[i*4+3] = bf2f(u.w);
  }
  f32x4 acc[4] = {};
  for (int d = 0; d < 64; ++d) {
    const float qd = qv[d];
    const f32x4* kr = (const f32x4*)(kvs + d * 64 + e0);
#pragma unroll
    for (int i = 0; i < 4; ++i) acc[i] += qd * kr[i];
  }
  u16* op = out + row * D_MODEL + h * 64 + e0;
#pragma unroll
  for (int i = 0; i < 4; ++i) {
    u16x4 o;
    o.x = f2bf(acc[i][0]); o.y = f2bf(acc[i][1]);
    o.z = f2bf(acc[i][2]); o.w = f2bf(acc[i][3]);
    ((u16x4*)op)[i] = o;
  }
}

// ---------------------------------------------------------------------------
// Inputs fp32, OUTPUT FP32. Workspace (peak 128 MB), lifetime-packed:
//   [0,32)MB   : transposed bf16 weights; kvpart (4MB fp32) aliases wkt+wvt
//   [32,64)MB  : hb (LN1 out, bf16)  -> x1b (attn+res, bf16)
//   [64,96)MB  : kb (K) -> qb (Q) -> hb2 (LN2)
//   [96,128)MB : vb (V) -> attnb -> gbuf (FFN chunk, 32MB)
extern "C" void kernel_launch(void* const* d_in, const int* in_sizes, int n_in,
                              void* d_out, int out_size, void* d_ws, size_t ws_size,
                              hipStream_t stream)
{
  const float* x   = (const float*)d_in[0];
  const float* wq  = (const float*)d_in[1];
  const float* bq  = (const float*)d_in[2];
  const float* wk  = (const float*)d_in[3];
  const float* bk  = (const float*)d_in[4];
  const float* wv  = (const float*)d_in[5];
  const float* bv  = (const float*)d_in[6];
  const float* wo  = (const float*)d_in[7];
  const float* bo  = (const float*)d_in[8];
  const float* w1  = (const float*)d_in[9];
  const float* b1  = (const float*)d_in[10];
  const float* w2  = (const float*)d_in[11];
  const float* b2  = (const float*)d_in[12];
  const float* g1  = (const float*)d_in[13];
  const float* be1 = (const float*)d_in[14];
  const float* g2  = (const float*)d_in[15];
  const float* be2 = (const float*)d_in[16];

  char* ws = (char*)d_ws;
  const size_t MB = 1024ull * 1024ull;
  u16* wqt = (u16*)(ws + 0 * MB);
  u16* wkt = (u16*)(ws + 2 * MB);
  u16* wvt = (u16*)(ws + 4 * MB);
  u16* wot = (u16*)(ws + 6 * MB);
  u16* w1t = (u16*)(ws + 8 * MB);    // 16 MB
  u16* w2t = (u16*)(ws + 24 * MB);   // 8 MB

  u16* hb    = (u16*)(ws + 32 * MB); // LN1 out
  u16* x1b   = (u16*)(ws + 32 * MB); // alias: hb dead after Q gemm
  u16* kb    = (u16*)(ws + 64 * MB);
  u16* qb    = (u16*)(ws + 64 * MB); // alias: kb dead after kvmm_kernel
  u16* hb2   = (u16*)(ws + 64 * MB); // alias: qb dead after attn
  u16* vb    = (u16*)(ws + 96 * MB);
  u16* attnb = (u16*)(ws + 96 * MB); // alias: vb dead after kvmm_kernel
  u16* gbuf  = (u16*)(ws + 96 * MB); // alias: attnb dead after O gemm
  float* kvpart = (float*)(ws + 2 * MB); // alias wkt+wvt: dead after K/V gemms (4MB)

  // weight transposes + fp32->bf16 (N x K layout)
  transpose_kernel<<<dim3(32, 32), 256, 0, stream>>>(wq, wqt, 1024, 1024);
  transpose_kernel<<<dim3(32, 32), 256, 0, stream>>>(wk, wkt, 1024, 1024);
  transpose_kernel<<<dim3(32, 32), 256, 0, stream>>>(wv, wvt, 1024, 1024);
  transpose_kernel<<<dim3(32, 32), 256, 0, stream>>>(wo, wot, 1024, 1024);
  transpose_kernel<<<dim3(256, 32), 256, 0, stream>>>(w1, w1t, 1024, 8192);
  transpose_kernel<<<dim3(32, 128), 256, 0, stream>>>(w2, w2t, 4096, 1024);

  // LN1 (fp32 in -> bf16 out)
  ln_kernel<float><<<MROWS, 256, 0, stream>>>(x, g1, be1, hb);

  dim3 gproj(D_MODEL / 128, MROWS / BM);   // (8,128)
  // K, V first (consumed into kv), then Q overwrites kb
  gemm_kernel<1,128><<<gproj, 256, 0, stream>>>(hb, wkt, bk, nullptr, kb, D_MODEL, D_MODEL);
  gemm_kernel<0,128><<<gproj, 256, 0, stream>>>(hb, wvt, bv, nullptr, vb, D_MODEL, D_MODEL);

  // kv = K^T @ V (MFMA, 4 s-chunk partials + reduce; no atomics)
  kvmm_kernel<<<64 * 4, 256, 0, stream>>>(kb, vb, kvpart);
  kvreduce_kernel<<<256, 256, 0, stream>>>(kvpart);

  gemm_kernel<1,128><<<gproj, 256, 0, stream>>>(hb, wqt, bq, nullptr, qb, D_MODEL, D_MODEL);

  // attn = Q @ kv -> attnb (vb region)
  attn_kernel<<<BATCH * NHEAD * (SEQ / 64), 256, 0, stream>>>(qb, kvpart, attnb);

  // out projection + residual(x, fp32) -> x1b (hb region)
  gemm_kernel<2,128><<<gproj, 256, 0, stream>>>(attnb, wot, bo, x, x1b, D_MODEL, D_MODEL);

  // LN2 (bf16 in -> bf16 out) -> hb2 (qb region)
  ln_kernel<u16><<<MROWS, 256, 0, stream>>>(x1b, g2, be2, hb2);

  // FFN in row-chunks; gbuf (32 MB) reused per chunk; final out is FP32.
  // FFN2 uses BN=64 tiles: grid (16,32)=512 blocks = 2/CU (was 1/CU).
  for (int c = 0; c < MROWS / MCHUNK; ++c) {
    const size_t ro = (size_t)c * MCHUNK;
    ffn1_kernel<<<dim3(DFF / 128, MCHUNK / BM), 256, 0, stream>>>(
        hb2 + ro * D_MODEL, w1t, b1, gbuf, D_MODEL);
    gemm_kernel<3,64><<<dim3(D_MODEL / 64, MCHUNK / BM), 256, 0, stream>>>(
        gbuf, w2t, b2, x1b + ro * D_MODEL, (float*)d_out + ro * D_MODEL, D_MODEL, DFF);
  }
}